// Round 2
// baseline (340.401 us; speedup 1.0000x reference)
//
#include <hip/hip_runtime.h>
#include <math.h>

#define EPSF 1e-6f

__device__ __forceinline__ float iou_box(float ax1,float ay1,float ax2,float ay2,
                                         float bx1,float by1,float bx2,float by2) {
  float ix1 = fmaxf(ax1,bx1), iy1 = fmaxf(ay1,by1);
  float ix2 = fminf(ax2,bx2), iy2 = fminf(ay2,by2);
  float inter = fmaxf(ix2-ix1,0.f)*fmaxf(iy2-iy1,0.f);
  float a1 = (ax2-ax1)*(ay2-ay1);
  float a2 = (bx2-bx1)*(by2-by1);
  float uni = a1+a2-inter;
  return inter/(uni+EPSF);
}

// insert packed value into descending-sorted triple
__device__ __forceinline__ void ins3(unsigned long long p,
                                     unsigned long long &t0,
                                     unsigned long long &t1,
                                     unsigned long long &t2) {
  if (p > t2) {
    if (p > t1) {
      if (p > t0) { t2 = t1; t1 = t0; t0 = p; }
      else        { t2 = t1; t1 = p; }
    } else t2 = p;
  }
}

__global__ void k_zero(unsigned int* __restrict__ forcedW, int nW,
                       unsigned int* __restrict__ accW, int nAcc,
                       float* __restrict__ out) {
  int i = blockIdx.x*blockDim.x + threadIdx.x;
  if (i < nW) forcedW[i] = 0u;
  if (i < nAcc) accW[i] = 0u;
  if (i == 0) out[0] = 0.f;
}

// one block per (b,t): exact top-3 anchors by IoU (tie: lower index first, matching lax.top_k)
// plus candidate count (iou > 0.3); writes forced flags for first k_t entries.
__global__ __launch_bounds__(256) void k_forced(
    const float4* __restrict__ anchors, const float4* __restrict__ tboxes,
    unsigned char* __restrict__ forced, int A, int T) {
  int p = blockIdx.x;
  int b = p / T, t = p - b*T;
  float4 tb = tboxes[b*T + t];
  int tid = threadIdx.x;
  unsigned long long q0=0ull, q1=0ull, q2=0ull;
  int cand = 0;
  for (int a = tid; a < A; a += 256) {
    float4 an = anchors[a];
    float iou = iou_box(an.x,an.y,an.z,an.w, tb.x,tb.y,tb.z,tb.w);
    cand += (iou > 0.3f) ? 1 : 0;
    unsigned long long pk = ((unsigned long long)__float_as_uint(iou) << 32)
                          | (unsigned long long)(0xFFFFFFFFu - (unsigned)a);
    ins3(pk, q0, q1, q2);
  }
  __shared__ unsigned long long s0[256], s1[256], s2[256];
  __shared__ int sc[256];
  s0[tid]=q0; s1[tid]=q1; s2[tid]=q2; sc[tid]=cand;
  __syncthreads();
  for (int s = 128; s > 0; s >>= 1) {
    if (tid < s) {
      unsigned long long a0=s0[tid], a1=s1[tid], a2=s2[tid];
      ins3(s0[tid+s], a0,a1,a2);
      ins3(s1[tid+s], a0,a1,a2);
      ins3(s2[tid+s], a0,a1,a2);
      s0[tid]=a0; s1[tid]=a1; s2[tid]=a2;
      sc[tid] += sc[tid+s];
    }
    __syncthreads();
  }
  if (tid == 0) {
    int nc = sc[0];
    int kt = nc < 1 ? 1 : (nc > 3 ? 3 : nc);
    unsigned long long tp[3] = {s0[0], s1[0], s2[0]};
    for (int j = 0; j < kt; ++j) {
      unsigned idx = 0xFFFFFFFFu - (unsigned)(tp[j] & 0xFFFFFFFFull);
      forced[(size_t)b*A + idx] = 1;  // races write same value; fine
    }
  }
}

// one thread per (b,a): max/argmax IoU, pos/neg, focal, bbox loss for positives.
__global__ __launch_bounds__(256) void k_anchor(
    const float4* __restrict__ bbox_pred, const float* __restrict__ conf_pred,
    const float4* __restrict__ anchors, const float4* __restrict__ tboxes,
    const unsigned char* __restrict__ forced,
    unsigned int* __restrict__ negBits,
    float* __restrict__ accPos, float* __restrict__ accBbox,
    unsigned int* __restrict__ cntPos, unsigned int* __restrict__ cntNeg,
    int A, int T) {
  int b = blockIdx.y;
  int a = blockIdx.x * blockDim.x + threadIdx.x;
  int tid = threadIdx.x;
  __shared__ float4 st[128];
  if (tid < T) st[tid] = tboxes[b*T + tid];
  __syncthreads();
  bool valid = (a < A);
  float focal = 0.f, bboxTerm = 0.f;
  bool isPos = false, isNeg = false;
  if (valid) {
    float4 an = anchors[a];
    float maxI = -1.f; int bt = 0;
    for (int t = 0; t < T; ++t) {
      float4 tb = st[t];
      float iou = iou_box(an.x,an.y,an.z,an.w, tb.x,tb.y,tb.z,tb.w);
      if (iou > maxI) { maxI = iou; bt = t; }   // strict > : first occurrence, matches argmax
    }
    size_t ia = (size_t)b * A + a;
    isPos = (maxI >= 0.5f) || (forced[ia] != 0);
    isNeg = (maxI < 0.4f) && !isPos;
    float conf = conf_pred[ia];
    float pt = isPos ? conf : (1.f - conf);
    float ptc = fminf(fmaxf(pt, EPSF), 1.f - EPSF);
    float om = 1.f - pt;
    focal = -(isPos ? 0.25f : 0.75f) * om * om * logf(ptc);
    negBits[ia] = isNeg ? __float_as_uint(focal) : 0u;  // focal > 0 strictly for valid conf
    if (isPos) {
      float4 pb = bbox_pred[ia];
      float4 m = st[bt];
      float ix1 = fmaxf(pb.x, m.x), iy1 = fmaxf(pb.y, m.y);
      float ix2 = fminf(pb.z, m.z), iy2 = fminf(pb.w, m.w);
      float inter = fmaxf(ix2-ix1, 0.f) * fmaxf(iy2-iy1, 0.f);
      float a1 = (pb.z-pb.x)*(pb.w-pb.y);
      float a2 = (m.z-m.x)*(m.w-m.y);
      float uni = a1 + a2 - inter;
      float iou = inter / (uni + EPSF);
      float ex1 = fminf(pb.x, m.x), ey1 = fminf(pb.y, m.y);
      float ex2 = fmaxf(pb.z, m.z), ey2 = fmaxf(pb.w, m.w);
      float enc = (ex2-ex1)*(ey2-ey1);
      float giou = iou - (enc - uni)/(enc + EPSF);
      float l1 = fabsf(pb.x-m.x)+fabsf(pb.y-m.y)+fabsf(pb.z-m.z)+fabsf(pb.w-m.w);
      bboxTerm = (1.f - giou) + 0.125f * l1;  // 0.5 * mean over 4 coords
    }
  }
  __shared__ float sP[256], sB[256];
  __shared__ int cP[256], cN[256];
  sP[tid] = isPos ? focal : 0.f;
  sB[tid] = bboxTerm;
  cP[tid] = isPos ? 1 : 0;
  cN[tid] = isNeg ? 1 : 0;
  __syncthreads();
  for (int s = 128; s > 0; s >>= 1) {
    if (tid < s) { sP[tid]+=sP[tid+s]; sB[tid]+=sB[tid+s]; cP[tid]+=cP[tid+s]; cN[tid]+=cN[tid+s]; }
    __syncthreads();
  }
  if (tid == 0) {
    atomicAdd(&accPos[b], sP[0]);
    atomicAdd(&accBbox[b], sB[0]);
    atomicAdd(&cntPos[b], (unsigned)cP[0]);
    atomicAdd(&cntNeg[b], (unsigned)cN[0]);
  }
}

// one block per image: radix-select k-th largest negative focal (bit-exact on fp32 bits),
// sum top-k, finalize the scalar.
__global__ __launch_bounds__(1024) void k_finalize(
    const unsigned int* __restrict__ negBits,
    const float* __restrict__ accPos, const float* __restrict__ accBbox,
    const unsigned int* __restrict__ cntPos, const unsigned int* __restrict__ cntNeg,
    float* __restrict__ out, int A, int B) {
  int b = blockIdx.x;
  int tid = threadIdx.x;
  const unsigned int* nb = negBits + (size_t)b * A;
  int np = (int)cntPos[b];
  int nn = (int)cntNeg[b];
  int ratio = (np > 0) ? min(3, A / np) : 0;
  int maxneg = ratio * np;
  int k = min(maxneg, nn);

  __shared__ unsigned int hist[256];
  __shared__ unsigned int sPrefix;
  __shared__ int sKrem;
  __shared__ float ssum[1024];
  __shared__ int scnt[1024];

  float negSum = 0.f;
  if (k > 0) {  // uniform branch across block
    unsigned prefix = 0; int krem = k;
    for (int r = 0; r < 4; ++r) {
      int shift = 24 - 8*r;
      unsigned maskHi = (r == 0) ? 0u : (0xFFFFFFFFu << (32 - 8*r));
      if (tid < 256) hist[tid] = 0;
      __syncthreads();
      for (int a = tid; a < A; a += blockDim.x) {
        unsigned v = nb[a];
        if ((v & maskHi) == prefix) atomicAdd(&hist[(v >> shift) & 0xFFu], 1u);
      }
      __syncthreads();
      if (tid == 0) {
        unsigned cum = 0; int sel = 0;
        for (int j = 255; j >= 0; --j) {
          unsigned c = hist[j];
          if (cum + c >= (unsigned)krem) { sel = j; break; }
          cum += c;
        }
        sPrefix = prefix | ((unsigned)sel << shift);
        sKrem = krem - (int)cum;
      }
      __syncthreads();
      prefix = sPrefix; krem = sKrem;
      __syncthreads();
    }
    unsigned theta = prefix;
    float thf = __uint_as_float(theta);
    float ls = 0.f; int lc = 0;
    for (int a = tid; a < A; a += blockDim.x) {
      unsigned v = nb[a];
      if (v > theta) { ls += __uint_as_float(v); lc++; }
    }
    ssum[tid] = ls; scnt[tid] = lc;
    __syncthreads();
    for (int s = (int)blockDim.x >> 1; s > 0; s >>= 1) {
      if (tid < s) { ssum[tid] += ssum[tid+s]; scnt[tid] += scnt[tid+s]; }
      __syncthreads();
    }
    negSum = ssum[0] + (float)(k - scnt[0]) * thf;  // ties at cutoff have value == thf: exact
  }
  if (tid == 0) {
    float confL = (accPos[b] + negSum) / (float)max(np + k, 1);
    float bboxL = accBbox[b] / (float)(np > 0 ? np : 1);
    atomicAdd(out, (confL + bboxL) / (float)B);
  }
}

extern "C" void kernel_launch(void* const* d_in, const int* in_sizes, int n_in,
                              void* d_out, int out_size, void* d_ws, size_t ws_size,
                              hipStream_t stream) {
  const float4* bbox_pred = (const float4*)d_in[0];
  const float*  conf_pred = (const float*)d_in[1];
  const float4* anchors   = (const float4*)d_in[2];
  const float4* tboxes    = (const float4*)d_in[3];
  float* out = (float*)d_out;

  int A = in_sizes[2] / 4;          // 65536
  int B = in_sizes[1] / A;          // 16
  int T = in_sizes[3] / (4 * B);    // 32

  // workspace layout: negBits[B*A] u32 | forced[B*A] u8 | accPos[B] f32 | accBbox[B] f32 | cntPos[B] u32 | cntNeg[B] u32
  unsigned int* negBits = (unsigned int*)d_ws;
  unsigned char* forced = (unsigned char*)(negBits + (size_t)B * A);
  float* accPos  = (float*)(forced + (size_t)B * A);
  float* accBbox = accPos + B;
  unsigned int* cntPos = (unsigned int*)(accBbox + B);
  unsigned int* cntNeg = cntPos + B;

  int nForcedW = (B * A) / 4;
  int nAcc = 4 * B;
  int nzMax = nForcedW > nAcc ? nForcedW : nAcc;
  k_zero<<<(nzMax + 255) / 256, 256, 0, stream>>>((unsigned int*)forced, nForcedW,
                                                  (unsigned int*)accPos, nAcc, out);

  k_forced<<<B * T, 256, 0, stream>>>(anchors, tboxes, forced, A, T);

  dim3 g2((A + 255) / 256, (unsigned)B);
  k_anchor<<<g2, 256, 0, stream>>>(bbox_pred, conf_pred, anchors, tboxes, forced,
                                   negBits, accPos, accBbox, cntPos, cntNeg, A, T);

  k_finalize<<<B, 1024, 0, stream>>>(negBits, accPos, accBbox, cntPos, cntNeg, out, A, B);
}

// Round 3
// 290.378 us; speedup vs baseline: 1.1723x; 1.1723x over previous
//
#include <hip/hip_runtime.h>
#include <math.h>

#define EPSF 1e-6f
#define ACH 2048     // anchors per k_fpart block
#define NBIN 1024    // conf histogram bins
#define CAP 8192     // cutoff-bucket collect capacity (expected ~64 for uniform conf)

struct Part { unsigned long long q0, q1, q2, cand; };

__device__ __forceinline__ float iou_box(float ax1,float ay1,float ax2,float ay2,
                                         float bx1,float by1,float bx2,float by2) {
  float ix1 = fmaxf(ax1,bx1), iy1 = fmaxf(ay1,by1);
  float ix2 = fminf(ax2,bx2), iy2 = fminf(ay2,by2);
  float inter = fmaxf(ix2-ix1,0.f)*fmaxf(iy2-iy1,0.f);
  float a1 = (ax2-ax1)*(ay2-ay1);
  float a2 = (bx2-bx1)*(by2-by1);
  float uni = a1+a2-inter;
  return inter/(uni+EPSF);
}

__device__ __forceinline__ void ins3(unsigned long long p,
                                     unsigned long long &t0,
                                     unsigned long long &t1,
                                     unsigned long long &t2) {
  if (p > t2) {
    if (p > t1) {
      if (p > t0) { t2 = t1; t1 = t0; t0 = p; }
      else        { t2 = t1; t1 = p; }
    } else t2 = p;
  }
}

__device__ __forceinline__ float focal_neg(float c) {
  // focal for a negative anchor with conf c (alpha_f = 0.75), mirrors k_anchor exactly
  float pt = 1.f - c;
  float ptc = fminf(fmaxf(pt, EPSF), 1.f - EPSF);
  float om = 1.f - pt;
  return -0.75f * om * om * logf(ptc);
}

__global__ void k_zero(unsigned int* __restrict__ fw, int nfw,
                       unsigned int* __restrict__ gh, int ngh,
                       unsigned int* __restrict__ acc, int nacc,
                       float* __restrict__ out) {
  int i = blockIdx.x*blockDim.x + threadIdx.x;
  if (i < nfw) fw[i] = 0u;
  if (i < ngh) gh[i] = 0u;
  if (i < nacc) acc[i] = 0u;
  if (i == 0) out[0] = 0.f;
}

// block = (anchor chunk, image). LDS-stage 2048 anchors once; 256 threads = 8 anchor
// groups x 32 targets. Each thread: top-3 (packed iou|~idx, lower index wins ties,
// matching lax.top_k) + candidate count for its (chunk-slice, target).
__global__ __launch_bounds__(256) void k_fpart(
    const float4* __restrict__ anchors, const float4* __restrict__ tboxes,
    Part* __restrict__ parts, int A, int T, int nch) {
  __shared__ float4 sa[ACH];
  int chunk = blockIdx.x, b = blockIdx.y;
  int tid = threadIdx.x;
  int base = chunk * ACH;
  for (int i = tid; i < ACH; i += 256) sa[i] = anchors[base + i];
  int t = tid & 31, g = tid >> 5;
  int tc = t < T ? t : T - 1;
  float4 tb = tboxes[b*T + tc];
  __syncthreads();
  unsigned long long q0=0ull, q1=0ull, q2=0ull; unsigned cand = 0;
  for (int i = g; i < ACH; i += 8) {
    float4 an = sa[i];   // 2 distinct addrs per wave -> 2-way broadcast, free
    float iou = iou_box(an.x,an.y,an.z,an.w, tb.x,tb.y,tb.z,tb.w);
    cand += iou > 0.3f ? 1u : 0u;
    unsigned long long pk = ((unsigned long long)__float_as_uint(iou) << 32)
                          | (unsigned long long)(0xFFFFFFFFu - (unsigned)(base + i));
    ins3(pk, q0, q1, q2);
  }
  __shared__ unsigned long long s0[256], s1[256], s2[256];
  __shared__ unsigned sc[256];
  s0[tid]=q0; s1[tid]=q1; s2[tid]=q2; sc[tid]=cand;
  __syncthreads();
  // partners at stride >=32 share t -> merges the 8 anchor-groups per target
  for (int s = 128; s >= 32; s >>= 1) {
    if (tid < s) {
      unsigned long long a0=s0[tid], a1=s1[tid], a2=s2[tid];
      ins3(s0[tid+s],a0,a1,a2); ins3(s1[tid+s],a0,a1,a2); ins3(s2[tid+s],a0,a1,a2);
      s0[tid]=a0; s1[tid]=a1; s2[tid]=a2; sc[tid]+=sc[tid+s];
    }
    __syncthreads();
  }
  if (tid < 32 && tid < T) {
    Part p; p.q0=s0[tid]; p.q1=s1[tid]; p.q2=s2[tid]; p.cand=sc[tid];
    parts[(b*T + tid)*nch + chunk] = p;
  }
}

// one wave per (b,t): merge nch chunk-partials -> forced flags for first k_t entries
__global__ __launch_bounds__(64) void k_fmerge(
    const Part* __restrict__ parts, unsigned char* __restrict__ forced,
    int A, int T, int nch) {
  int p = blockIdx.x;            // b*T + t
  int b = p / T;
  int lane = threadIdx.x;
  unsigned long long q0=0ull, q1=0ull, q2=0ull, cand=0ull;
  if (lane < 32) {
    for (int c = lane; c < nch; c += 32) {
      Part pp = parts[p*nch + c];
      ins3(pp.q0,q0,q1,q2); ins3(pp.q1,q0,q1,q2); ins3(pp.q2,q0,q1,q2);
      cand += pp.cand;
    }
  }
  for (int s = 1; s < 32; s <<= 1) {
    unsigned long long r0=__shfl_xor(q0,s,64), r1=__shfl_xor(q1,s,64), r2=__shfl_xor(q2,s,64);
    unsigned long long rc=__shfl_xor(cand,s,64);
    ins3(r0,q0,q1,q2); ins3(r1,q0,q1,q2); ins3(r2,q0,q1,q2);
    cand += rc;
  }
  if (lane == 0) {
    int nc = (int)cand;
    int kt = nc < 1 ? 1 : (nc > 3 ? 3 : nc);
    unsigned long long tp[3] = {q0,q1,q2};
    for (int j = 0; j < kt; ++j) {
      unsigned idx = 0xFFFFFFFFu - (unsigned)(tp[j] & 0xFFFFFFFFull);
      forced[(size_t)b*A + idx] = 1;
    }
  }
}

// one thread per (b,a): max/argmax IoU, pos/neg, focal, bbox loss for positives.
// writes negConf = conf if negative else -1 (focal is strictly increasing in conf
// for negatives, so top-k by focal == top-k by conf, ties coincide).
__global__ __launch_bounds__(256) void k_anchor(
    const float4* __restrict__ bbox_pred, const float* __restrict__ conf_pred,
    const float4* __restrict__ anchors, const float4* __restrict__ tboxes,
    const unsigned char* __restrict__ forced,
    float* __restrict__ negConf,
    float* __restrict__ accPos, float* __restrict__ accBbox,
    unsigned int* __restrict__ cntPos, unsigned int* __restrict__ cntNeg,
    int A, int T) {
  int b = blockIdx.y;
  int a = blockIdx.x * blockDim.x + threadIdx.x;
  int tid = threadIdx.x;
  __shared__ float4 st[128];
  if (tid < T) st[tid] = tboxes[b*T + tid];
  __syncthreads();
  bool valid = (a < A);
  float focal = 0.f, bboxTerm = 0.f;
  bool isPos = false, isNeg = false;
  if (valid) {
    float4 an = anchors[a];
    float maxI = -1.f; int bt = 0;
    for (int t = 0; t < T; ++t) {
      float4 tb = st[t];
      float iou = iou_box(an.x,an.y,an.z,an.w, tb.x,tb.y,tb.z,tb.w);
      if (iou > maxI) { maxI = iou; bt = t; }   // strict >: first occurrence, matches argmax
    }
    size_t ia = (size_t)b * A + a;
    isPos = (maxI >= 0.5f) || (forced[ia] != 0);
    isNeg = (maxI < 0.4f) && !isPos;
    float conf = conf_pred[ia];
    float pt = isPos ? conf : (1.f - conf);
    float ptc = fminf(fmaxf(pt, EPSF), 1.f - EPSF);
    float om = 1.f - pt;
    focal = -(isPos ? 0.25f : 0.75f) * om * om * logf(ptc);
    negConf[ia] = isNeg ? conf : -1.f;
    if (isPos) {
      float4 pb = bbox_pred[ia];
      float4 m = st[bt];
      float ix1 = fmaxf(pb.x, m.x), iy1 = fmaxf(pb.y, m.y);
      float ix2 = fminf(pb.z, m.z), iy2 = fminf(pb.w, m.w);
      float inter = fmaxf(ix2-ix1, 0.f) * fmaxf(iy2-iy1, 0.f);
      float a1 = (pb.z-pb.x)*(pb.w-pb.y);
      float a2 = (m.z-m.x)*(m.w-m.y);
      float uni = a1 + a2 - inter;
      float iou = inter / (uni + EPSF);
      float ex1 = fminf(pb.x, m.x), ey1 = fminf(pb.y, m.y);
      float ex2 = fmaxf(pb.z, m.z), ey2 = fmaxf(pb.w, m.w);
      float enc = (ex2-ex1)*(ey2-ey1);
      float giou = iou - (enc - uni)/(enc + EPSF);
      float l1 = fabsf(pb.x-m.x)+fabsf(pb.y-m.y)+fabsf(pb.z-m.z)+fabsf(pb.w-m.w);
      bboxTerm = (1.f - giou) + 0.125f * l1;
    }
  }
  __shared__ float sP[256], sB[256];
  __shared__ int cP[256], cN[256];
  sP[tid] = isPos ? focal : 0.f;
  sB[tid] = bboxTerm;
  cP[tid] = isPos ? 1 : 0;
  cN[tid] = isNeg ? 1 : 0;
  __syncthreads();
  for (int s = 128; s > 0; s >>= 1) {
    if (tid < s) { sP[tid]+=sP[tid+s]; sB[tid]+=sB[tid+s]; cP[tid]+=cP[tid+s]; cN[tid]+=cN[tid+s]; }
    __syncthreads();
  }
  if (tid == 0) {
    atomicAdd(&accPos[b], sP[0]);
    atomicAdd(&accBbox[b], sB[0]);
    atomicAdd(&cntPos[b], (unsigned)cP[0]);
    atomicAdd(&cntNeg[b], (unsigned)cN[0]);
  }
}

// per-image 1024-bin histogram of negative conf (uniform bins -> ~no contention)
__global__ __launch_bounds__(256) void k_hist(
    const float* __restrict__ negConf, unsigned int* __restrict__ gh, int A) {
  __shared__ unsigned h[NBIN];
  int b = blockIdx.y;
  int tid = threadIdx.x;
  for (int i = tid; i < NBIN; i += 256) h[i] = 0;
  __syncthreads();
  const float4* nc4 = (const float4*)(negConf + (size_t)b * A);
  int per = (A/4) / gridDim.x;
  int i0 = blockIdx.x * per;
  for (int i = tid; i < per; i += 256) {
    float4 c4 = nc4[i0 + i];
    float cs[4] = {c4.x, c4.y, c4.z, c4.w};
    #pragma unroll
    for (int j = 0; j < 4; ++j) {
      float c = cs[j];
      if (c >= 0.f) {
        int bin = min(NBIN-1, (int)(c * 1024.f));
        atomicAdd(&h[bin], 1u);
      }
    }
  }
  __syncthreads();
  for (int i = tid; i < NBIN; i += 256)
    if (h[i]) atomicAdd(&gh[b*NBIN + i], h[i]);
}

// per image: suffix-scan histogram -> cutoff bucket; sum focal for bins above;
// exact tie-resolving radix among the (few) bucket members.
__global__ __launch_bounds__(1024) void k_final(
    const float* __restrict__ negConf, const unsigned int* __restrict__ gh,
    const float* __restrict__ accPos, const float* __restrict__ accBbox,
    const unsigned int* __restrict__ cntPos, const unsigned int* __restrict__ cntNeg,
    float* __restrict__ out, int A, int B) {
  int b = blockIdx.x, tid = threadIdx.x;
  int np = (int)cntPos[b], nn = (int)cntNeg[b];
  int ratio = (np > 0) ? min(3, A / np) : 0;
  int k = min(ratio * np, nn);

  __shared__ unsigned sc[NBIN];
  __shared__ int sSelB, sKrem;
  __shared__ unsigned bcount;
  __shared__ unsigned buf[CAP];
  __shared__ float sred[1024];
  __shared__ unsigned sredc[1024];
  __shared__ unsigned hist[256];
  __shared__ unsigned sTheta; __shared__ int sKr2;

  float negSum = 0.f;
  if (k > 0) {
    // inclusive scan of reversed hist -> suffix sums S[bkt] = sc[NBIN-1-bkt]
    sc[tid] = gh[b*NBIN + (NBIN-1-tid)];
    __syncthreads();
    for (int off = 1; off < NBIN; off <<= 1) {
      unsigned add = (tid >= off) ? sc[tid-off] : 0u;
      __syncthreads();
      sc[tid] += add;
      __syncthreads();
    }
    {
      unsigned Sb  = sc[NBIN-1-tid];
      unsigned Snx = (tid == NBIN-1) ? 0u : sc[NBIN-2-tid];
      if (Sb >= (unsigned)k && Snx < (unsigned)k) { sSelB = tid; sKrem = k - (int)Snx; }
      if (tid == 0) bcount = 0;
    }
    __syncthreads();
    int selB = sSelB, krem = sKrem;

    // pass 1: sum focal for bins > selB; collect bucket-selB conf bits
    float ls = 0.f;
    const float4* nc4 = (const float4*)(negConf + (size_t)b * A);
    int n4 = A / 4;
    for (int i = tid; i < n4; i += 1024) {
      float4 c4 = nc4[i];
      float cs[4] = {c4.x, c4.y, c4.z, c4.w};
      #pragma unroll
      for (int j = 0; j < 4; ++j) {
        float c = cs[j];
        if (c >= 0.f) {
          int bin = min(NBIN-1, (int)(c * 1024.f));
          if (bin > selB) ls += focal_neg(c);
          else if (bin == selB) {
            unsigned idx = atomicAdd(&bcount, 1u);
            if (idx < CAP) buf[idx] = __float_as_uint(c);
          }
        }
      }
    }
    sred[tid] = ls;
    __syncthreads();
    for (int s = 512; s > 0; s >>= 1) { if (tid < s) sred[tid] += sred[tid+s]; __syncthreads(); }
    float sum_hi = sred[0];
    int m = (int)min(bcount, (unsigned)CAP);  // uniform conf: bcount ~ 64 << CAP

    // radix-select krem-th largest conf among the m bucket members
    unsigned prefix = 0; int kr = krem;
    for (int r = 0; r < 4; ++r) {
      int shift = 24 - 8*r;
      unsigned maskHi = (r == 0) ? 0u : (0xFFFFFFFFu << (32 - 8*r));
      if (tid < 256) hist[tid] = 0;
      __syncthreads();
      for (int i2 = tid; i2 < m; i2 += 1024) {
        unsigned v = buf[i2];
        if ((v & maskHi) == prefix) atomicAdd(&hist[(v >> shift) & 0xFFu], 1u);
      }
      __syncthreads();
      if (tid == 0) {
        unsigned cum = 0; int sel = 0;
        for (int j = 255; j >= 0; --j) {
          unsigned c = hist[j];
          if (cum + c >= (unsigned)kr) { sel = j; break; }
          cum += c;
        }
        sTheta = prefix | ((unsigned)sel << shift);
        sKr2 = kr - (int)cum;
      }
      __syncthreads();
      prefix = sTheta; kr = sKr2;
      __syncthreads();
    }
    unsigned theta = prefix;

    // pass 2 over bucket: strictly-greater sum + count; ties correction is exact
    float ls2 = 0.f; unsigned lc2 = 0;
    for (int i2 = tid; i2 < m; i2 += 1024) {
      unsigned v = buf[i2];
      if (v > theta) { ls2 += focal_neg(__uint_as_float(v)); lc2++; }
    }
    sred[tid] = ls2; sredc[tid] = lc2;
    __syncthreads();
    for (int s = 512; s > 0; s >>= 1) {
      if (tid < s) { sred[tid] += sred[tid+s]; sredc[tid] += sredc[tid+s]; }
      __syncthreads();
    }
    negSum = sum_hi + sred[0] + (float)(krem - (int)sredc[0]) * focal_neg(__uint_as_float(theta));
  }
  if (tid == 0) {
    float confL = (accPos[b] + negSum) / (float)max(np + k, 1);
    float bboxL = accBbox[b] / (float)(np > 0 ? np : 1);
    atomicAdd(out, (confL + bboxL) / (float)B);
  }
}

extern "C" void kernel_launch(void* const* d_in, const int* in_sizes, int n_in,
                              void* d_out, int out_size, void* d_ws, size_t ws_size,
                              hipStream_t stream) {
  const float4* bbox_pred = (const float4*)d_in[0];
  const float*  conf_pred = (const float*)d_in[1];
  const float4* anchors   = (const float4*)d_in[2];
  const float4* tboxes    = (const float4*)d_in[3];
  float* out = (float*)d_out;

  int A = in_sizes[2] / 4;          // 65536
  int B = in_sizes[1] / A;          // 16
  int T = in_sizes[3] / (4 * B);    // 32
  int nch = A / ACH;                // 32

  // ws: negConf f32[B*A] | forced u8[B*A] | parts[B*T*nch] | gh u32[B*NBIN] | acc
  float* negConf = (float*)d_ws;
  unsigned char* forced = (unsigned char*)(negConf + (size_t)B*A);
  Part* parts = (Part*)(forced + (size_t)B*A);
  unsigned int* gh = (unsigned int*)(parts + (size_t)B*T*nch);
  float* accPos  = (float*)(gh + (size_t)B*NBIN);
  float* accBbox = accPos + B;
  unsigned int* cntPos = (unsigned int*)(accBbox + B);
  unsigned int* cntNeg = cntPos + B;

  int nfw = (B * A) / 4;            // forced as u32 words
  int ngh = B * NBIN;
  int nacc = 4 * B;
  k_zero<<<(nfw + 255) / 256, 256, 0, stream>>>((unsigned int*)forced, nfw, gh, ngh,
                                                (unsigned int*)accPos, nacc, out);

  dim3 gf((unsigned)(A / ACH), (unsigned)B);
  k_fpart<<<gf, 256, 0, stream>>>(anchors, tboxes, parts, A, T, nch);
  k_fmerge<<<B * T, 64, 0, stream>>>(parts, forced, A, T, nch);

  dim3 g2((unsigned)(A / 256), (unsigned)B);
  k_anchor<<<g2, 256, 0, stream>>>(bbox_pred, conf_pred, anchors, tboxes, forced,
                                   negConf, accPos, accBbox, cntPos, cntNeg, A, T);

  dim3 gh_(16, (unsigned)B);
  k_hist<<<gh_, 256, 0, stream>>>(negConf, gh, A);
  k_final<<<B, 1024, 0, stream>>>(negConf, gh, accPos, accBbox, cntPos, cntNeg, out, A, B);
}

// Round 4
// 171.859 us; speedup vs baseline: 1.9807x; 1.6896x over previous
//
#include <hip/hip_runtime.h>
#include <math.h>

#define EPSF 1e-6f
#define ACH 512      // anchors per k_fpart block (2048 blocks -> full occupancy)
#define NBIN 1024    // conf histogram bins
#define CAP 8192     // cutoff-bucket collect capacity (expected ~64 for uniform conf)

struct Part { unsigned long long q0, q1, q2; unsigned long long cand; };

#define BIASU 0x4000000000000000ull

__device__ __forceinline__ double u2d(unsigned long long x) {
  return __longlong_as_double((long long)x);
}
__device__ __forceinline__ unsigned long long d2u(double x) {
  return (unsigned long long)__double_as_longlong(x);
}

// branchless sorted-insert into descending triple; keys are positive doubles
// (bit62 bias set, exponent never all-ones) so f64 order == u64 order.
__device__ __forceinline__ void ins3d(double p, double &q0, double &q1, double &q2) {
  double n0 = fmax(q0, p), x = fmin(q0, p);
  double n1 = fmax(q1, x), y = fmin(q1, x);
  double n2 = fmax(q2, y);
  q0 = n0; q1 = n1; q2 = n2;
}

__device__ __forceinline__ float focal_neg(float c) {
  float pt = 1.f - c;
  float ptc = fminf(fmaxf(pt, EPSF), 1.f - EPSF);
  float om = 1.f - pt;
  return -0.75f * om * om * logf(ptc);
}

__global__ void k_zero(unsigned int* __restrict__ fw, int nfw,
                       unsigned int* __restrict__ gh, int ngh,
                       unsigned int* __restrict__ acc, int nacc,
                       float* __restrict__ out) {
  int i = blockIdx.x*blockDim.x + threadIdx.x;
  if (i < nfw) fw[i] = 0u;
  if (i < ngh) gh[i] = 0u;
  if (i < nacc) acc[i] = 0u;
  if (i == 0) out[0] = 0.f;
}

// block = (512-anchor chunk, image). 256 threads = 8 anchor-groups x 32 targets.
// Branchless per-thread top-3 (packed iou|~idx: lower index wins ties, matching
// lax.top_k) + candidate count; LDS tree-merge across groups per target.
__global__ __launch_bounds__(256, 8) void k_fpart(
    const float4* __restrict__ anchors, const float4* __restrict__ tboxes,
    Part* __restrict__ parts, int A, int T, int nch) {
  __shared__ float4 sa[ACH];
  __shared__ double s0[256], s1[256], s2[256];
  __shared__ unsigned sc[256];
  int chunk = blockIdx.x, b = blockIdx.y;
  int tid = threadIdx.x;
  int base = chunk * ACH;
  for (int i = tid; i < ACH; i += 256) sa[i] = anchors[base + i];
  int t = tid & 31, g = tid >> 5;
  int tc = t < T ? t : T - 1;
  float4 tb = tboxes[b*T + tc];
  float tarea = (tb.z - tb.x) * (tb.w - tb.y);
  __syncthreads();
  const double BIASD = u2d(BIASU);
  double q0 = BIASD, q1 = BIASD, q2 = BIASD;
  unsigned cand = 0;
  for (int i = g; i < ACH; i += 8) {
    float4 an = sa[i];   // 2 distinct addrs per wave -> LDS broadcast, conflict-free
    float ix1 = fmaxf(an.x, tb.x), iy1 = fmaxf(an.y, tb.y);
    float ix2 = fminf(an.z, tb.z), iy2 = fminf(an.w, tb.w);
    float inter = fmaxf(ix2-ix1, 0.f) * fmaxf(iy2-iy1, 0.f);
    float a1 = (an.z-an.x)*(an.w-an.y);
    float uni = a1 + tarea - inter;
    float iou = inter / (uni + EPSF);
    cand += iou > 0.3f ? 1u : 0u;
    unsigned long long pk = ((unsigned long long)__float_as_uint(iou) << 32)
                          | (unsigned long long)(0xFFFFFFFFu - (unsigned)(base + i))
                          | BIASU;
    ins3d(u2d(pk), q0, q1, q2);
  }
  s0[tid]=q0; s1[tid]=q1; s2[tid]=q2; sc[tid]=cand;
  __syncthreads();
  // partners at stride >=32 share t -> merges the 8 anchor-groups per target
  for (int s = 128; s >= 32; s >>= 1) {
    if (tid < s) {
      double a0=s0[tid], a1=s1[tid], a2=s2[tid];
      ins3d(s0[tid+s], a0,a1,a2);
      ins3d(s1[tid+s], a0,a1,a2);
      ins3d(s2[tid+s], a0,a1,a2);
      s0[tid]=a0; s1[tid]=a1; s2[tid]=a2; sc[tid]+=sc[tid+s];
    }
    __syncthreads();
  }
  if (tid < 32 && tid < T) {
    Part p; p.q0=d2u(s0[tid]); p.q1=d2u(s1[tid]); p.q2=d2u(s2[tid]); p.cand=sc[tid];
    parts[(b*T + tid)*nch + chunk] = p;
  }
}

// one wave per (b,t): merge nch chunk-partials -> forced flags for first k_t entries
__global__ __launch_bounds__(64) void k_fmerge(
    const Part* __restrict__ parts, unsigned char* __restrict__ forced,
    int A, int T, int nch) {
  int p = blockIdx.x;            // b*T + t
  int b = p / T;
  int lane = threadIdx.x;
  const double BIASD = u2d(BIASU);
  double q0=BIASD, q1=BIASD, q2=BIASD;
  unsigned long long cand = 0;
  for (int c = lane; c < nch; c += 64) {
    Part pp = parts[p*nch + c];
    ins3d(u2d(pp.q0),q0,q1,q2); ins3d(u2d(pp.q1),q0,q1,q2); ins3d(u2d(pp.q2),q0,q1,q2);
    cand += pp.cand;
  }
  for (int s = 1; s < 64; s <<= 1) {
    double r0=__shfl_xor(q0,s,64), r1=__shfl_xor(q1,s,64), r2=__shfl_xor(q2,s,64);
    unsigned long long rc=__shfl_xor(cand,s,64);
    ins3d(r0,q0,q1,q2); ins3d(r1,q0,q1,q2); ins3d(r2,q0,q1,q2);
    cand += rc;
  }
  if (lane == 0) {
    int nc = (int)cand;
    int kt = nc < 1 ? 1 : (nc > 3 ? 3 : nc);
    unsigned long long tp[3] = {d2u(q0), d2u(q1), d2u(q2)};
    for (int j = 0; j < kt; ++j) {
      unsigned idx = 0xFFFFFFFFu - (unsigned)(tp[j] & 0xFFFFFFFFull);
      forced[(size_t)b*A + idx] = 1;
    }
  }
}

// 2 anchors per thread; unrolled target loop (2 independent max-chains per LDS read).
// negConf = conf if negative else -1 (focal strictly increasing in conf for negatives).
__global__ __launch_bounds__(256, 4) void k_anchor(
    const float4* __restrict__ bbox_pred, const float* __restrict__ conf_pred,
    const float4* __restrict__ anchors, const float4* __restrict__ tboxes,
    const unsigned char* __restrict__ forced,
    float* __restrict__ negConf,
    float* __restrict__ accPos, float* __restrict__ accBbox,
    unsigned int* __restrict__ cntPos, unsigned int* __restrict__ cntNeg,
    int A, int T) {
  int b = blockIdx.y;
  int tid = threadIdx.x;
  __shared__ float4 st[32];
  if (tid < T) st[tid] = tboxes[b*T + tid];
  __syncthreads();
  int aA = blockIdx.x * 512 + tid;
  int aB = aA + 256;
  float4 anA = anchors[aA], anB = anchors[aB];
  float arA = (anA.z-anA.x)*(anA.w-anA.y);
  float arB = (anB.z-anB.x)*(anB.w-anB.y);
  float maxA = -1.f, maxB = -1.f;
  int btA = 0, btB = 0;
  #pragma unroll 8
  for (int tt = 0; tt < T; ++tt) {
    float4 tb = st[tt];
    float ta = (tb.z-tb.x)*(tb.w-tb.y);
    {
      float ix1=fmaxf(anA.x,tb.x), iy1=fmaxf(anA.y,tb.y);
      float ix2=fminf(anA.z,tb.z), iy2=fminf(anA.w,tb.w);
      float inter=fmaxf(ix2-ix1,0.f)*fmaxf(iy2-iy1,0.f);
      float iou = inter / (arA + ta - inter + EPSF);
      bool gtn = iou > maxA; maxA = gtn ? iou : maxA; btA = gtn ? tt : btA;
    }
    {
      float ix1=fmaxf(anB.x,tb.x), iy1=fmaxf(anB.y,tb.y);
      float ix2=fminf(anB.z,tb.z), iy2=fminf(anB.w,tb.w);
      float inter=fmaxf(ix2-ix1,0.f)*fmaxf(iy2-iy1,0.f);
      float iou = inter / (arB + ta - inter + EPSF);
      bool gtn = iou > maxB; maxB = gtn ? iou : maxB; btB = gtn ? tt : btB;
    }
  }
  float fsum = 0.f, bsum = 0.f;
  int cpos = 0, cneg = 0;
  #pragma unroll
  for (int h = 0; h < 2; ++h) {
    int a = h ? aB : aA;
    float maxI = h ? maxB : maxA;
    int bt = h ? btB : btA;
    size_t ia = (size_t)b * A + a;
    bool isPos = (maxI >= 0.5f) || (forced[ia] != 0);
    bool isNeg = (maxI < 0.4f) && !isPos;
    float conf = conf_pred[ia];
    float pt = isPos ? conf : (1.f - conf);
    float ptc = fminf(fmaxf(pt, EPSF), 1.f - EPSF);
    float om = 1.f - pt;
    float focal = -(isPos ? 0.25f : 0.75f) * om * om * logf(ptc);
    negConf[ia] = isNeg ? conf : -1.f;
    // branchless bbox term (positives ~ few %, but nearly every wave has one)
    float4 pb = bbox_pred[ia];
    float4 m = st[bt];
    float ix1 = fmaxf(pb.x, m.x), iy1 = fmaxf(pb.y, m.y);
    float ix2 = fminf(pb.z, m.z), iy2 = fminf(pb.w, m.w);
    float inter = fmaxf(ix2-ix1, 0.f) * fmaxf(iy2-iy1, 0.f);
    float a1 = (pb.z-pb.x)*(pb.w-pb.y);
    float a2 = (m.z-m.x)*(m.w-m.y);
    float uni = a1 + a2 - inter;
    float iou = inter / (uni + EPSF);
    float ex1 = fminf(pb.x, m.x), ey1 = fminf(pb.y, m.y);
    float ex2 = fmaxf(pb.z, m.z), ey2 = fmaxf(pb.w, m.w);
    float enc = (ex2-ex1)*(ey2-ey1);
    float giou = iou - (enc - uni)/(enc + EPSF);
    float l1 = fabsf(pb.x-m.x)+fabsf(pb.y-m.y)+fabsf(pb.z-m.z)+fabsf(pb.w-m.w);
    float bterm = (1.f - giou) + 0.125f * l1;
    fsum += isPos ? focal : 0.f;
    bsum += isPos ? bterm : 0.f;
    cpos += isPos ? 1 : 0;
    cneg += isNeg ? 1 : 0;
  }
  __shared__ float sP[256], sB[256];
  __shared__ int cP[256], cN[256];
  sP[tid]=fsum; sB[tid]=bsum; cP[tid]=cpos; cN[tid]=cneg;
  __syncthreads();
  for (int s = 128; s > 0; s >>= 1) {
    if (tid < s) { sP[tid]+=sP[tid+s]; sB[tid]+=sB[tid+s]; cP[tid]+=cP[tid+s]; cN[tid]+=cN[tid+s]; }
    __syncthreads();
  }
  if (tid == 0) {
    atomicAdd(&accPos[b], sP[0]);
    atomicAdd(&accBbox[b], sB[0]);
    atomicAdd(&cntPos[b], (unsigned)cP[0]);
    atomicAdd(&cntNeg[b], (unsigned)cN[0]);
  }
}

// per-image 1024-bin histogram of negative conf (uniform bins -> ~no contention)
__global__ __launch_bounds__(256) void k_hist(
    const float* __restrict__ negConf, unsigned int* __restrict__ gh, int A) {
  __shared__ unsigned h[NBIN];
  int b = blockIdx.y;
  int tid = threadIdx.x;
  for (int i = tid; i < NBIN; i += 256) h[i] = 0;
  __syncthreads();
  const float4* nc4 = (const float4*)(negConf + (size_t)b * A);
  int per = (A/4) / gridDim.x;
  int i0 = blockIdx.x * per;
  for (int i = tid; i < per; i += 256) {
    float4 c4 = nc4[i0 + i];
    float cs[4] = {c4.x, c4.y, c4.z, c4.w};
    #pragma unroll
    for (int j = 0; j < 4; ++j) {
      float c = cs[j];
      if (c >= 0.f) {
        int bin = min(NBIN-1, (int)(c * 1024.f));
        atomicAdd(&h[bin], 1u);
      }
    }
  }
  __syncthreads();
  for (int i = tid; i < NBIN; i += 256)
    if (h[i]) atomicAdd(&gh[b*NBIN + i], h[i]);
}

// per image: suffix-scan histogram -> cutoff bucket; sum focal for bins above;
// exact tie-resolving radix among the (few) bucket members.
__global__ __launch_bounds__(1024) void k_final(
    const float* __restrict__ negConf, const unsigned int* __restrict__ gh,
    const float* __restrict__ accPos, const float* __restrict__ accBbox,
    const unsigned int* __restrict__ cntPos, const unsigned int* __restrict__ cntNeg,
    float* __restrict__ out, int A, int B) {
  int b = blockIdx.x, tid = threadIdx.x;
  int np = (int)cntPos[b], nn = (int)cntNeg[b];
  int ratio = (np > 0) ? min(3, A / np) : 0;
  int k = min(ratio * np, nn);

  __shared__ unsigned sc[NBIN];
  __shared__ int sSelB, sKrem;
  __shared__ unsigned bcount;
  __shared__ unsigned buf[CAP];
  __shared__ float sred[1024];
  __shared__ unsigned sredc[1024];
  __shared__ unsigned hist[256];
  __shared__ unsigned sTheta; __shared__ int sKr2;

  float negSum = 0.f;
  if (k > 0) {
    sc[tid] = gh[b*NBIN + (NBIN-1-tid)];
    __syncthreads();
    for (int off = 1; off < NBIN; off <<= 1) {
      unsigned add = (tid >= off) ? sc[tid-off] : 0u;
      __syncthreads();
      sc[tid] += add;
      __syncthreads();
    }
    {
      unsigned Sb  = sc[NBIN-1-tid];
      unsigned Snx = (tid == NBIN-1) ? 0u : sc[NBIN-2-tid];
      if (Sb >= (unsigned)k && Snx < (unsigned)k) { sSelB = tid; sKrem = k - (int)Snx; }
      if (tid == 0) bcount = 0;
    }
    __syncthreads();
    int selB = sSelB, krem = sKrem;

    float ls = 0.f;
    const float4* nc4 = (const float4*)(negConf + (size_t)b * A);
    int n4 = A / 4;
    for (int i = tid; i < n4; i += 1024) {
      float4 c4 = nc4[i];
      float cs[4] = {c4.x, c4.y, c4.z, c4.w};
      #pragma unroll
      for (int j = 0; j < 4; ++j) {
        float c = cs[j];
        if (c >= 0.f) {
          int bin = min(NBIN-1, (int)(c * 1024.f));
          if (bin > selB) ls += focal_neg(c);
          else if (bin == selB) {
            unsigned idx = atomicAdd(&bcount, 1u);
            if (idx < CAP) buf[idx] = __float_as_uint(c);
          }
        }
      }
    }
    sred[tid] = ls;
    __syncthreads();
    for (int s = 512; s > 0; s >>= 1) { if (tid < s) sred[tid] += sred[tid+s]; __syncthreads(); }
    float sum_hi = sred[0];
    int m = (int)min(bcount, (unsigned)CAP);

    unsigned prefix = 0; int kr = krem;
    for (int r = 0; r < 4; ++r) {
      int shift = 24 - 8*r;
      unsigned maskHi = (r == 0) ? 0u : (0xFFFFFFFFu << (32 - 8*r));
      if (tid < 256) hist[tid] = 0;
      __syncthreads();
      for (int i2 = tid; i2 < m; i2 += 1024) {
        unsigned v = buf[i2];
        if ((v & maskHi) == prefix) atomicAdd(&hist[(v >> shift) & 0xFFu], 1u);
      }
      __syncthreads();
      if (tid == 0) {
        unsigned cum = 0; int sel = 0;
        for (int j = 255; j >= 0; --j) {
          unsigned c = hist[j];
          if (cum + c >= (unsigned)kr) { sel = j; break; }
          cum += c;
        }
        sTheta = prefix | ((unsigned)sel << shift);
        sKr2 = kr - (int)cum;
      }
      __syncthreads();
      prefix = sTheta; kr = sKr2;
      __syncthreads();
    }
    unsigned theta = prefix;

    float ls2 = 0.f; unsigned lc2 = 0;
    for (int i2 = tid; i2 < m; i2 += 1024) {
      unsigned v = buf[i2];
      if (v > theta) { ls2 += focal_neg(__uint_as_float(v)); lc2++; }
    }
    sred[tid] = ls2; sredc[tid] = lc2;
    __syncthreads();
    for (int s = 512; s > 0; s >>= 1) {
      if (tid < s) { sred[tid] += sred[tid+s]; sredc[tid] += sredc[tid+s]; }
      __syncthreads();
    }
    negSum = sum_hi + sred[0] + (float)(krem - (int)sredc[0]) * focal_neg(__uint_as_float(theta));
  }
  if (tid == 0) {
    float confL = (accPos[b] + negSum) / (float)max(np + k, 1);
    float bboxL = accBbox[b] / (float)(np > 0 ? np : 1);
    atomicAdd(out, (confL + bboxL) / (float)B);
  }
}

extern "C" void kernel_launch(void* const* d_in, const int* in_sizes, int n_in,
                              void* d_out, int out_size, void* d_ws, size_t ws_size,
                              hipStream_t stream) {
  const float4* bbox_pred = (const float4*)d_in[0];
  const float*  conf_pred = (const float*)d_in[1];
  const float4* anchors   = (const float4*)d_in[2];
  const float4* tboxes    = (const float4*)d_in[3];
  float* out = (float*)d_out;

  int A = in_sizes[2] / 4;          // 65536
  int B = in_sizes[1] / A;          // 16
  int T = in_sizes[3] / (4 * B);    // 32
  int nch = A / ACH;                // 128

  // ws: negConf f32[B*A] | forced u8[B*A] | parts[B*T*nch] | gh u32[B*NBIN] | acc
  float* negConf = (float*)d_ws;
  unsigned char* forced = (unsigned char*)(negConf + (size_t)B*A);
  Part* parts = (Part*)(forced + (size_t)B*A);
  unsigned int* gh = (unsigned int*)(parts + (size_t)B*T*nch);
  float* accPos  = (float*)(gh + (size_t)B*NBIN);
  float* accBbox = accPos + B;
  unsigned int* cntPos = (unsigned int*)(accBbox + B);
  unsigned int* cntNeg = cntPos + B;

  int nfw = (B * A) / 4;
  int ngh = B * NBIN;
  int nacc = 4 * B;
  k_zero<<<(nfw + 255) / 256, 256, 0, stream>>>((unsigned int*)forced, nfw, gh, ngh,
                                                (unsigned int*)accPos, nacc, out);

  dim3 gf((unsigned)nch, (unsigned)B);
  k_fpart<<<gf, 256, 0, stream>>>(anchors, tboxes, parts, A, T, nch);
  k_fmerge<<<B * T, 64, 0, stream>>>(parts, forced, A, T, nch);

  dim3 g2((unsigned)(A / 512), (unsigned)B);
  k_anchor<<<g2, 256, 0, stream>>>(bbox_pred, conf_pred, anchors, tboxes, forced,
                                   negConf, accPos, accBbox, cntPos, cntNeg, A, T);

  dim3 gh_(16, (unsigned)B);
  k_hist<<<gh_, 256, 0, stream>>>(negConf, gh, A);
  k_final<<<B, 1024, 0, stream>>>(negConf, gh, accPos, accBbox, cntPos, cntNeg, out, A, B);
}

// Round 6
// 116.161 us; speedup vs baseline: 2.9304x; 1.4795x over previous
//
#include <hip/hip_runtime.h>
#include <math.h>

#define EPSF 1e-6f
#define ACH 512      // anchors per k_fpart block
#define NBIN 1024    // conf histogram bins
#define CAP 8192     // cutoff-bucket capacity (expected ~64 for uniform conf)
#define BIASU 0x4000000000000000ull

struct Part { unsigned long long q0, q1, q2, cand; };

__device__ __forceinline__ double u2d(unsigned long long x){return __longlong_as_double((long long)x);}
__device__ __forceinline__ unsigned long long d2u(double x){return (unsigned long long)__double_as_longlong(x);}

// branchless sorted-insert into descending triple; keys are positive doubles
// (bit62 bias, exponent never all-ones) so f64 order == u64 order.
__device__ __forceinline__ void ins3d(double p, double &q0, double &q1, double &q2) {
  double n0 = fmax(q0,p), x = fmin(q0,p);
  double n1 = fmax(q1,x), y = fmin(q1,x);
  double n2 = fmax(q2,y);
  q0=n0; q1=n1; q2=n2;
}

__device__ __forceinline__ float focal_neg(float c) {
  float pt = 1.f - c;
  float ptc = fminf(fmaxf(pt, EPSF), 1.f - EPSF);
  float om = 1.f - pt;
  return -0.75f * om * om * logf(ptc);
}

__global__ void k_zero(unsigned* __restrict__ fw, int nfw,
                       unsigned* __restrict__ gh, int ngh,
                       unsigned* __restrict__ acc, int nacc,
                       float* __restrict__ out) {
  int i = blockIdx.x*blockDim.x + threadIdx.x;
  if (i < nfw) fw[i] = 0u;
  if (i < ngh) gh[i] = 0u;
  if (i < nacc) acc[i] = 0u;
  if (i == 0) out[0] = 0.f;
}

// block = (512-anchor chunk, image). Loop 1 (target-major): per-target top-3
// (packed iou|~idx: lower index wins ties, matching lax.top_k) + cand count.
// Loop 2 (anchor-major): per-anchor max/argmax over T -> maxIou/bestT (strict >
// = first occurrence, matching argmax). Anchors read once from HBM per block.
__global__ __launch_bounds__(256, 6) void k_fpart(
    const float4* __restrict__ anchors, const float4* __restrict__ tboxes,
    Part* __restrict__ parts, float* __restrict__ maxIou, unsigned char* __restrict__ bestT,
    int A, int T, int nch) {
  __shared__ float4 sa[ACH];
  __shared__ float4 st[32];
  __shared__ double s0[256], s1[256], s2[256];
  __shared__ unsigned sc[256];
  int chunk = blockIdx.x, b = blockIdx.y;
  int tid = threadIdx.x;
  int base = chunk * ACH;
  for (int i = tid; i < ACH; i += 256) sa[i] = anchors[base + i];
  if (tid < T) st[tid] = tboxes[b*T + tid];
  int t = tid & 31, g = tid >> 5;
  float4 tb = tboxes[b*T + (t < T ? t : T-1)];
  float tarea = (tb.z-tb.x)*(tb.w-tb.y);
  __syncthreads();
  const double BIASD = u2d(BIASU);
  double q0=BIASD, q1=BIASD, q2=BIASD;
  unsigned cand = 0;
  for (int i = g; i < ACH; i += 8) {
    float4 an = sa[i];   // 2 distinct addrs/wave -> LDS broadcast
    float ix1=fmaxf(an.x,tb.x), iy1=fmaxf(an.y,tb.y);
    float ix2=fminf(an.z,tb.z), iy2=fminf(an.w,tb.w);
    float inter=fmaxf(ix2-ix1,0.f)*fmaxf(iy2-iy1,0.f);
    float a1=(an.z-an.x)*(an.w-an.y);
    float iou = inter/(a1+tarea-inter+EPSF);
    cand += iou>0.3f ? 1u : 0u;
    unsigned long long pk = ((unsigned long long)__float_as_uint(iou)<<32)
                          | (unsigned long long)(0xFFFFFFFFu-(unsigned)(base+i)) | BIASU;
    ins3d(u2d(pk), q0,q1,q2);
  }
  s0[tid]=q0; s1[tid]=q1; s2[tid]=q2; sc[tid]=cand;
  __syncthreads();
  for (int s=128; s>=32; s>>=1) {
    if (tid<s) {
      double a0=s0[tid], a1=s1[tid], a2=s2[tid];
      ins3d(s0[tid+s],a0,a1,a2); ins3d(s1[tid+s],a0,a1,a2); ins3d(s2[tid+s],a0,a1,a2);
      s0[tid]=a0; s1[tid]=a1; s2[tid]=a2; sc[tid]+=sc[tid+s];
    }
    __syncthreads();
  }
  if (tid<32 && tid<T) {
    Part p; p.q0=d2u(s0[tid]); p.q1=d2u(s1[tid]); p.q2=d2u(s2[tid]); p.cand=sc[tid];
    parts[(b*T+tid)*nch+chunk]=p;
  }
  // loop 2: per-anchor max/argmax (reads sa/st only; no extra sync needed)
  #pragma unroll
  for (int h = 0; h < 2; ++h) {
    int i = tid + h*256;
    float4 an = sa[i];
    float ar = (an.z-an.x)*(an.w-an.y);
    float mx = -1.f; int bt = 0;
    #pragma unroll 8
    for (int tt = 0; tt < T; ++tt) {
      float4 tv = st[tt];
      float ta2=(tv.z-tv.x)*(tv.w-tv.y);
      float ix1=fmaxf(an.x,tv.x), iy1=fmaxf(an.y,tv.y);
      float ix2=fminf(an.z,tv.z), iy2=fminf(an.w,tv.w);
      float inter=fmaxf(ix2-ix1,0.f)*fmaxf(iy2-iy1,0.f);
      float iou = inter/(ar+ta2-inter+EPSF);
      bool gt = iou > mx; mx = gt?iou:mx; bt = gt?tt:bt;
    }
    maxIou[(size_t)b*A + base + i] = mx;
    bestT[(size_t)b*A + base + i] = (unsigned char)bt;
  }
}

// one wave per (b,t): merge nch chunk-partials -> forced flags for first k_t entries
__global__ __launch_bounds__(64) void k_fmerge(
    const Part* __restrict__ parts, unsigned char* __restrict__ forced,
    int A, int T, int nch) {
  int p = blockIdx.x;            // b*T + t
  int b = p / T;
  int lane = threadIdx.x;
  const double BIASD = u2d(BIASU);
  double q0=BIASD, q1=BIASD, q2=BIASD;
  unsigned long long cand = 0;
  for (int c = lane; c < nch; c += 64) {
    Part pp = parts[p*nch + c];
    ins3d(u2d(pp.q0),q0,q1,q2); ins3d(u2d(pp.q1),q0,q1,q2); ins3d(u2d(pp.q2),q0,q1,q2);
    cand += pp.cand;
  }
  for (int s = 1; s < 64; s <<= 1) {
    double r0=__shfl_xor(q0,s,64), r1=__shfl_xor(q1,s,64), r2=__shfl_xor(q2,s,64);
    unsigned long long rc=__shfl_xor(cand,s,64);
    ins3d(r0,q0,q1,q2); ins3d(r1,q0,q1,q2); ins3d(r2,q0,q1,q2);
    cand += rc;
  }
  if (lane == 0) {
    int nc = (int)cand;
    int kt = nc < 1 ? 1 : (nc > 3 ? 3 : nc);
    unsigned long long tp[3] = {d2u(q0), d2u(q1), d2u(q2)};
    for (int j = 0; j < kt; ++j) {
      unsigned idx = 0xFFFFFFFFu - (unsigned)(tp[j] & 0xFFFFFFFFull);
      forced[(size_t)b*A + idx] = 1;
    }
  }
}

// streaming: 16 anchors/thread. Reads maxIou/bestT/forced/conf (+bbox for positives),
// writes negConf, builds per-image conf histogram (LDS->global), accumulates
// focal/bbox sums + counts. No IoU recompute.
__global__ __launch_bounds__(256) void k_anchor2(
    const float4* __restrict__ bbox_pred, const float* __restrict__ conf_pred,
    const float4* __restrict__ tboxes,
    const unsigned char* __restrict__ forced, const float* __restrict__ maxIou,
    const unsigned char* __restrict__ bestT,
    float* __restrict__ negConf, unsigned* __restrict__ gh,
    float* __restrict__ accPos, float* __restrict__ accBbox,
    unsigned* __restrict__ cntPos, unsigned* __restrict__ cntNeg,
    int A, int T) {
  __shared__ float4 st[32];
  __shared__ unsigned h[NBIN];
  __shared__ float sP[256], sB[256];
  __shared__ int cP[256], cN[256];
  int b = blockIdx.y, tid = threadIdx.x;
  if (tid < T) st[tid] = tboxes[b*T+tid];
  for (int i = tid; i < NBIN; i += 256) h[i] = 0;
  __syncthreads();
  size_t ibase = (size_t)b*A + (size_t)blockIdx.x*4096;
  float fsum=0.f, bsum=0.f; int cpos=0, cneg=0;
  for (int it = 0; it < 4; ++it) {
    int off = it*1024 + tid*4;
    float4 mi4 = *(const float4*)(maxIou + ibase + off);
    float4 cf4 = *(const float4*)(conf_pred + ibase + off);
    uchar4 fc4 = *(const uchar4*)(forced + ibase + off);
    uchar4 bt4 = *(const uchar4*)(bestT + ibase + off);
    float mis[4]={mi4.x,mi4.y,mi4.z,mi4.w};
    float cfs[4]={cf4.x,cf4.y,cf4.z,cf4.w};
    unsigned char fcs[4]={fc4.x,fc4.y,fc4.z,fc4.w};
    unsigned char bts[4]={bt4.x,bt4.y,bt4.z,bt4.w};
    float nc[4];
    #pragma unroll
    for (int j=0;j<4;++j) {
      float maxI = mis[j], conf = cfs[j];
      bool isPos = (maxI >= 0.5f) || (fcs[j] != 0);
      bool isNeg = (maxI < 0.4f) && !isPos;
      nc[j] = isNeg ? conf : -1.f;
      if (isNeg) {
        int bin = min(NBIN-1, (int)(conf*1024.f));
        atomicAdd(&h[bin], 1u);
        cneg++;
      }
      if (isPos) {
        cpos++;
        float ptc = fminf(fmaxf(conf, EPSF), 1.f-EPSF);
        float om = 1.f - conf;
        fsum += -0.25f * om * om * logf(ptc);
        float4 pb = bbox_pred[ibase + off + j];
        float4 m = st[bts[j]];
        float ix1=fmaxf(pb.x,m.x), iy1=fmaxf(pb.y,m.y);
        float ix2=fminf(pb.z,m.z), iy2=fminf(pb.w,m.w);
        float inter=fmaxf(ix2-ix1,0.f)*fmaxf(iy2-iy1,0.f);
        float a1=(pb.z-pb.x)*(pb.w-pb.y);
        float a2=(m.z-m.x)*(m.w-m.y);
        float uni = a1 + a2 - inter;
        float iou = inter/(uni+EPSF);
        float ex1=fminf(pb.x,m.x), ey1=fminf(pb.y,m.y);
        float ex2=fmaxf(pb.z,m.z), ey2=fmaxf(pb.w,m.w);
        float enc=(ex2-ex1)*(ey2-ey1);
        float giou = iou - (enc-uni)/(enc+EPSF);
        float l1 = fabsf(pb.x-m.x)+fabsf(pb.y-m.y)+fabsf(pb.z-m.z)+fabsf(pb.w-m.w);
        bsum += (1.f - giou) + 0.125f*l1;
      }
    }
    *(float4*)(negConf + ibase + off) = make_float4(nc[0],nc[1],nc[2],nc[3]);
  }
  sP[tid]=fsum; sB[tid]=bsum; cP[tid]=cpos; cN[tid]=cneg;
  __syncthreads();
  for (int s=128;s>0;s>>=1) {
    if (tid<s){ sP[tid]+=sP[tid+s]; sB[tid]+=sB[tid+s]; cP[tid]+=cP[tid+s]; cN[tid]+=cN[tid+s]; }
    __syncthreads();
  }
  if (tid==0) {
    atomicAdd(&accPos[b], sP[0]);
    atomicAdd(&accBbox[b], sB[0]);
    atomicAdd(&cntPos[b], (unsigned)cP[0]);
    atomicAdd(&cntNeg[b], (unsigned)cN[0]);
  }
  for (int i = tid; i < NBIN; i += 256)
    if (h[i]) atomicAdd(&gh[b*NBIN + i], h[i]);
}

// 16 blocks/image: redundant parallel hist-scan -> selB/krem, then stream slice:
// focal-sum for bins > selB, collect cutoff-bucket members to global.
__global__ __launch_bounds__(256) void k_collect(
    const float* __restrict__ negConf, const unsigned* __restrict__ gh,
    const unsigned* __restrict__ cntPos, const unsigned* __restrict__ cntNeg,
    float* __restrict__ sumHi, unsigned* __restrict__ bucketCnt,
    unsigned* __restrict__ bucketBuf, unsigned* __restrict__ kremG,
    int A, int B) {
  __shared__ unsigned hh[NBIN];
  __shared__ unsigned partial[256];
  __shared__ int sSelB, sKrem;
  __shared__ float sred[256];
  int b = blockIdx.y, tid = threadIdx.x;
  int np = (int)cntPos[b], nn = (int)cntNeg[b];
  int ratio = (np>0) ? min(3, A/np) : 0;
  int k = min(ratio*np, nn);
  if (k <= 0) return;
  for (int i = tid; i < NBIN; i += 256) hh[i] = gh[b*NBIN+i];
  __syncthreads();
  unsigned own = hh[4*tid] + hh[4*tid+1] + hh[4*tid+2] + hh[4*tid+3];
  partial[tid] = own;
  __syncthreads();
  for (int off=1; off<256; off<<=1) {       // inclusive suffix scan (parallel)
    unsigned v = (tid+off<256) ? partial[tid+off] : 0u;
    __syncthreads();
    partial[tid] += v;
    __syncthreads();
  }
  {
    unsigned running = partial[tid] - own;  // sum of bins >= 4(tid+1)
    #pragma unroll
    for (int j=3;j>=0;--j) {
      unsigned incl = running + hh[4*tid+j];
      if (incl >= (unsigned)k && running < (unsigned)k) { sSelB = 4*tid+j; sKrem = k-(int)running; }
      running = incl;
    }
  }
  __syncthreads();
  int selB = sSelB, krem = sKrem;
  if (blockIdx.x==0 && tid==0) kremG[b] = (unsigned)krem;
  const float4* nc4 = (const float4*)(negConf + (size_t)b*A);
  int per4 = (A/4) / gridDim.x;
  int i0 = blockIdx.x * per4;
  float ls = 0.f;
  for (int i = tid; i < per4; i += 256) {
    float4 c4 = nc4[i0+i];
    float cs[4]={c4.x,c4.y,c4.z,c4.w};
    #pragma unroll
    for (int j=0;j<4;++j) {
      float c = cs[j];
      if (c >= 0.f) {
        int bin = min(NBIN-1, (int)(c*1024.f));
        if (bin > selB) ls += focal_neg(c);
        else if (bin == selB) {
          unsigned idx = atomicAdd(&bucketCnt[b], 1u);
          if (idx < CAP) bucketBuf[b*CAP+idx] = __float_as_uint(c);
        }
      }
    }
  }
  sred[tid]=ls; __syncthreads();
  for (int s=128;s>0;s>>=1){ if(tid<s) sred[tid]+=sred[tid+s]; __syncthreads(); }
  if (tid==0) atomicAdd(&sumHi[b], sred[0]);
}

// one block/image: fully parallel radix-select (suffix-scan per round, no serial
// loops) over the small bucket -> exact theta; finalize scalar.
__global__ __launch_bounds__(256) void k_resolve(
    const unsigned* __restrict__ bucketBuf, const unsigned* __restrict__ bucketCnt,
    const unsigned* __restrict__ kremG, const float* __restrict__ sumHi,
    const float* __restrict__ accPos, const float* __restrict__ accBbox,
    const unsigned* __restrict__ cntPos, const unsigned* __restrict__ cntNeg,
    float* __restrict__ out, int A, int B) {
  __shared__ unsigned hist[256], suff[256];
  __shared__ unsigned sSel; __shared__ int sKr;
  __shared__ float sred[256]; __shared__ unsigned sredc[256];
  int b = blockIdx.x, tid = threadIdx.x;
  int np = (int)cntPos[b], nn = (int)cntNeg[b];
  int ratio = (np>0) ? min(3, A/np) : 0;
  int k = min(ratio*np, nn);
  float negSum = 0.f;
  if (k > 0) {
    int m = min((int)bucketCnt[b], CAP);
    int kr = (int)kremG[b];
    unsigned prefix = 0;
    const unsigned* buf = bucketBuf + b*CAP;
    for (int r=0;r<4;++r) {
      int shift = 24-8*r;
      unsigned maskHi = (r==0) ? 0u : (0xFFFFFFFFu << (32-8*r));
      hist[tid] = 0; __syncthreads();
      for (int i=tid;i<m;i+=256) {
        unsigned v = buf[i];
        if ((v & maskHi) == prefix) atomicAdd(&hist[(v>>shift)&0xFFu], 1u);
      }
      __syncthreads();
      suff[tid] = hist[tid]; __syncthreads();
      for (int off=1;off<256;off<<=1) {
        unsigned v = (tid+off<256) ? suff[tid+off] : 0u;
        __syncthreads(); suff[tid] += v; __syncthreads();
      }
      unsigned incl = suff[tid];
      unsigned above = (tid==255) ? 0u : suff[tid+1];
      if (incl >= (unsigned)kr && above < (unsigned)kr) { sSel=(unsigned)tid; sKr = kr-(int)above; }
      __syncthreads();
      prefix |= (sSel << shift); kr = sKr;
      __syncthreads();
    }
    unsigned theta = prefix;
    float ls=0.f; unsigned lc=0;
    for (int i=tid;i<m;i+=256) {
      unsigned v = buf[i];
      if (v > theta) { ls += focal_neg(__uint_as_float(v)); lc++; }
    }
    sred[tid]=ls; sredc[tid]=lc; __syncthreads();
    for (int s=128;s>0;s>>=1){
      if (tid<s){ sred[tid]+=sred[tid+s]; sredc[tid]+=sredc[tid+s]; }
      __syncthreads();
    }
    int krem = (int)kremG[b];
    negSum = sumHi[b] + sred[0] + (float)(krem-(int)sredc[0]) * focal_neg(__uint_as_float(theta));
  }
  if (tid==0) {
    float confL = (accPos[b] + negSum) / (float)max(np + k, 1);
    float bboxL = accBbox[b] / (float)(np > 0 ? np : 1);
    atomicAdd(out, (confL + bboxL) / (float)B);
  }
}

extern "C" void kernel_launch(void* const* d_in, const int* in_sizes, int n_in,
                              void* d_out, int out_size, void* d_ws, size_t ws_size,
                              hipStream_t stream) {
  const float4* bbox_pred = (const float4*)d_in[0];
  const float*  conf_pred = (const float*)d_in[1];
  const float4* anchors   = (const float4*)d_in[2];
  const float4* tboxes    = (const float4*)d_in[3];
  float* out = (float*)d_out;

  int A = in_sizes[2] / 4;          // 65536
  int B = in_sizes[1] / A;          // 16
  int T = in_sizes[3] / (4 * B);    // 32
  int nch = A / ACH;                // 128
  size_t BA = (size_t)B * A;

  // ws: negConf f32[BA] | maxIou f32[BA] | forced u8[BA] | bestT u8[BA] |
  //     parts[B*T*nch] | gh u32[B*NBIN] | bucketBuf u32[B*CAP] | small accs
  float* negConf = (float*)d_ws;
  float* maxIou  = negConf + BA;
  unsigned char* forced = (unsigned char*)(maxIou + BA);
  unsigned char* bestT  = forced + BA;
  Part* parts = (Part*)(bestT + BA);
  unsigned* gh = (unsigned*)(parts + (size_t)B*T*nch);
  unsigned* bucketBuf = gh + (size_t)B*NBIN;
  float* accPos  = (float*)(bucketBuf + (size_t)B*CAP);
  float* accBbox = accPos + B;
  unsigned* cntPos = (unsigned*)(accBbox + B);
  unsigned* cntNeg = cntPos + B;
  float* sumHi = (float*)(cntNeg + B);
  unsigned* bucketCnt = (unsigned*)(sumHi + B);
  unsigned* kremG = bucketCnt + B;

  int nfw = (int)(BA / 4);
  int ngh = B * NBIN;
  int nacc = 7 * B;   // accPos..kremG
  k_zero<<<(nfw + 255)/256, 256, 0, stream>>>((unsigned*)forced, nfw, gh, ngh,
                                              (unsigned*)accPos, nacc, out);

  dim3 gf((unsigned)nch, (unsigned)B);
  k_fpart<<<gf, 256, 0, stream>>>(anchors, tboxes, parts, maxIou, bestT, A, T, nch);
  k_fmerge<<<B*T, 64, 0, stream>>>(parts, forced, A, T, nch);

  dim3 g2((unsigned)(A/4096), (unsigned)B);
  k_anchor2<<<g2, 256, 0, stream>>>(bbox_pred, conf_pred, tboxes, forced, maxIou, bestT,
                                    negConf, gh, accPos, accBbox, cntPos, cntNeg, A, T);

  dim3 gc(16, (unsigned)B);
  k_collect<<<gc, 256, 0, stream>>>(negConf, gh, cntPos, cntNeg,
                                    sumHi, bucketCnt, bucketBuf, kremG, A, B);
  k_resolve<<<B, 256, 0, stream>>>(bucketBuf, bucketCnt, kremG, sumHi,
                                   accPos, accBbox, cntPos, cntNeg, out, A, B);
}

// Round 8
// 104.136 us; speedup vs baseline: 3.2688x; 1.1155x over previous
//
#include <hip/hip_runtime.h>
#include <math.h>

#define EPSF 1e-6f
#define ACH 512      // anchors per k_fpart block
#define NBIN 1024    // conf histogram bins
#define CAP 8192     // cutoff-bucket capacity (expected ~64 for uniform conf)
#define BIASU 0x4000000000000000ull

struct Part { unsigned long long q0, q1, q2, cand; };

__device__ __forceinline__ double u2d(unsigned long long x){return __longlong_as_double((long long)x);}
__device__ __forceinline__ unsigned long long d2u(double x){return (unsigned long long)__double_as_longlong(x);}

// branchless sorted-insert into descending triple; keys are positive doubles
// (bit62 bias, exponent never all-ones) so f64 order == u64 order.
__device__ __forceinline__ void ins3d(double p, double &q0, double &q1, double &q2) {
  double n0 = fmax(q0,p), x = fmin(q0,p);
  double n1 = fmax(q1,x), y = fmin(q1,x);
  double n2 = fmax(q2,y);
  q0=n0; q1=n1; q2=n2;
}

__device__ __forceinline__ float focal_neg(float c) {
  float pt = 1.f - c;
  float ptc = fminf(fmaxf(pt, EPSF), 1.f - EPSF);
  float om = 1.f - pt;
  return -0.75f * om * om * logf(ptc);
}

__global__ void k_zero(unsigned* __restrict__ fw, int nfw,
                       unsigned* __restrict__ gh, int ngh,
                       unsigned* __restrict__ acc, int nacc,
                       float* __restrict__ out) {
  int i = blockIdx.x*blockDim.x + threadIdx.x;
  if (i < nfw) fw[i] = 0u;
  if (i < ngh) gh[i] = 0u;
  if (i < nacc) acc[i] = 0u;
  if (i == 0) out[0] = 0.f;
}

// block = (512-anchor chunk, image).
// Loop 1 (target-major): top-3 AMONG CANDIDATES (iou>0.3) only — divisionless
// loose guard, exact np-bitwise iou test inside the rare guard. (Forced set is
// provably within candidates when num_cand>=1; cand==0 handled in k_fmerge.)
// Loop 2 (anchor-major): per-anchor max/argmax via cross-mult compare (no div
// in the loop); one precise division at the end -> maxIou matches np bitwise.
__global__ __launch_bounds__(256) void k_fpart(
    const float4* __restrict__ anchors, const float4* __restrict__ tboxes,
    Part* __restrict__ parts, float* __restrict__ maxIou, unsigned char* __restrict__ bestT,
    int A, int T, int nch) {
  __shared__ float4 sa[ACH];
  __shared__ float  saA[ACH];
  __shared__ float4 st[32];
  __shared__ float  stA[32];
  __shared__ double s0[256], s1[256], s2[256];
  __shared__ unsigned sc[256];
  int chunk = blockIdx.x, b = blockIdx.y;
  int tid = threadIdx.x;
  int base = chunk * ACH;
  for (int i = tid; i < ACH; i += 256) {
    float4 a = anchors[base + i];
    sa[i] = a; saA[i] = (a.z-a.x)*(a.w-a.y);
  }
  if (tid < T) {
    float4 tv = tboxes[b*T + tid];
    st[tid] = tv; stA[tid] = (tv.z-tv.x)*(tv.w-tv.y);
  }
  __syncthreads();
  int t = tid & 31, g = tid >> 5;
  int tc = t < T ? t : T - 1;
  float4 tb = st[tc];
  float ta = stA[tc];
  // guard: 1.3*inter >= 0.3*a1 + cH  covers iou>0.3 with ~7e-7 margin
  float cH = 0.3f*(ta + EPSF) - 1e-6f;
  const double BIASD = u2d(BIASU);
  double q0=BIASD, q1=BIASD, q2=BIASD;
  unsigned cand = 0;
  for (int i = g; i < ACH; i += 8) {
    float4 an = sa[i];          // 2 distinct addrs/wave -> LDS broadcast
    float a1 = saA[i];
    float ix1=fmaxf(an.x,tb.x), iy1=fmaxf(an.y,tb.y);
    float ix2=fminf(an.z,tb.z), iy2=fminf(an.w,tb.w);
    float inter=fmaxf(ix2-ix1,0.f)*fmaxf(iy2-iy1,0.f);
    if (1.3f*inter >= 0.3f*a1 + cH) {     // rare
      float u = (a1 + ta) - inter;
      float iou = inter / (u + EPSF);     // precise div, np-identical
      if (iou > 0.3f) {
        cand++;
        unsigned long long pk = ((unsigned long long)__float_as_uint(iou)<<32)
                              | (unsigned long long)(0xFFFFFFFFu-(unsigned)(base+i)) | BIASU;
        ins3d(u2d(pk), q0,q1,q2);
      }
    }
  }
  s0[tid]=q0; s1[tid]=q1; s2[tid]=q2; sc[tid]=cand;
  __syncthreads();
  for (int s=128; s>=32; s>>=1) {
    if (tid<s) {
      double a0=s0[tid], a1d=s1[tid], a2=s2[tid];
      ins3d(s0[tid+s],a0,a1d,a2); ins3d(s1[tid+s],a0,a1d,a2); ins3d(s2[tid+s],a0,a1d,a2);
      s0[tid]=a0; s1[tid]=a1d; s2[tid]=a2; sc[tid]+=sc[tid+s];
    }
    __syncthreads();
  }
  if (tid<32 && tid<T) {
    Part p; p.q0=d2u(s0[tid]); p.q1=d2u(s1[tid]); p.q2=d2u(s2[tid]); p.cand=sc[tid];
    parts[(b*T+tid)*nch+chunk]=p;
  }
  // loop 2: per-anchor max/argmax, division-free compare
  #pragma unroll
  for (int h = 0; h < 2; ++h) {
    int i = tid + h*256;
    float4 an = sa[i];
    float a1 = saA[i];
    float bn = -1.f, bd = 1.f; int bt = 0;
    #pragma unroll 8
    for (int tt = 0; tt < T; ++tt) {
      float4 tv = st[tt];
      float ix1=fmaxf(an.x,tv.x), iy1=fmaxf(an.y,tv.y);
      float ix2=fminf(an.z,tv.z), iy2=fminf(an.w,tv.w);
      float inter=fmaxf(ix2-ix1,0.f)*fmaxf(iy2-iy1,0.f);
      float u = (a1 + stA[tt]) - inter;
      float d = u + EPSF;                 // same op order as np reference
      bool gt = inter*bd > bn*d;          // iou_new > iou_best (cross-mult, d,bd>0)
      bn = gt?inter:bn; bd = gt?d:bd; bt = gt?tt:bt;
    }
    maxIou[(size_t)b*A + base + i] = bn / bd;   // precise: matches np inter/(u+eps)
    bestT[(size_t)b*A + base + i] = (unsigned char)bt;
  }
}

// one wave per (b,t): merge nch chunk-partials. If cand>=1 forced = first
// min(3,cand) of merged candidate top-3 (== reference's top-kt). If cand==0
// (vanishing prob.), exact fallback: full-A argmax scan with np-identical iou.
__global__ __launch_bounds__(64) void k_fmerge(
    const Part* __restrict__ parts, const float4* __restrict__ anchors,
    const float4* __restrict__ tboxes, unsigned char* __restrict__ forced,
    int A, int T, int nch) {
  int p = blockIdx.x;            // b*T + t
  int b = p / T, t = p - b*T;
  int lane = threadIdx.x;
  const double BIASD = u2d(BIASU);
  double q0=BIASD, q1=BIASD, q2=BIASD;
  unsigned long long cand = 0;
  for (int c = lane; c < nch; c += 64) {
    Part pp = parts[p*nch + c];
    ins3d(u2d(pp.q0),q0,q1,q2); ins3d(u2d(pp.q1),q0,q1,q2); ins3d(u2d(pp.q2),q0,q1,q2);
    cand += pp.cand;
  }
  for (int s = 1; s < 64; s <<= 1) {
    double r0=__shfl_xor(q0,s,64), r1=__shfl_xor(q1,s,64), r2=__shfl_xor(q2,s,64);
    unsigned long long rc=__shfl_xor(cand,s,64);
    ins3d(r0,q0,q1,q2); ins3d(r1,q0,q1,q2); ins3d(r2,q0,q1,q2);
    cand += rc;
  }
  if (cand == 0) {               // wave-uniform, ~never taken
    float4 tv = tboxes[b*T + t];
    float ta = (tv.z-tv.x)*(tv.w-tv.y);
    double m = BIASD;
    for (int a = lane; a < A; a += 64) {
      float4 an = anchors[a];
      float a1 = (an.z-an.x)*(an.w-an.y);
      float ix1=fmaxf(an.x,tv.x), iy1=fmaxf(an.y,tv.y);
      float ix2=fminf(an.z,tv.z), iy2=fminf(an.w,tv.w);
      float inter=fmaxf(ix2-ix1,0.f)*fmaxf(iy2-iy1,0.f);
      float u = (a1 + ta) - inter;
      float iou = inter / (u + EPSF);
      unsigned long long pk = ((unsigned long long)__float_as_uint(iou)<<32)
                            | (unsigned long long)(0xFFFFFFFFu-(unsigned)a) | BIASU;
      m = fmax(m, u2d(pk));
    }
    for (int s = 1; s < 64; s <<= 1) m = fmax(m, __shfl_xor(m, s, 64));
    if (lane == 0) {
      unsigned idx = 0xFFFFFFFFu - (unsigned)(d2u(m) & 0xFFFFFFFFull);
      forced[(size_t)b*A + idx] = 1;
    }
  } else if (lane == 0) {
    int kt = cand > 3 ? 3 : (int)cand;
    unsigned long long tp[3] = {d2u(q0), d2u(q1), d2u(q2)};
    for (int j = 0; j < kt; ++j) {
      unsigned idx = 0xFFFFFFFFu - (unsigned)(tp[j] & 0xFFFFFFFFull);
      forced[(size_t)b*A + idx] = 1;
    }
  }
}

// streaming: 16 anchors/thread. Reads maxIou/bestT/forced/conf (+bbox for positives),
// writes negConf, builds per-image conf histogram (LDS->global), accumulates
// focal/bbox sums + counts.
__global__ __launch_bounds__(256) void k_anchor2(
    const float4* __restrict__ bbox_pred, const float* __restrict__ conf_pred,
    const float4* __restrict__ tboxes,
    const unsigned char* __restrict__ forced, const float* __restrict__ maxIou,
    const unsigned char* __restrict__ bestT,
    float* __restrict__ negConf, unsigned* __restrict__ gh,
    float* __restrict__ accPos, float* __restrict__ accBbox,
    unsigned* __restrict__ cntPos, unsigned* __restrict__ cntNeg,
    int A, int T) {
  __shared__ float4 st[32];
  __shared__ unsigned h[NBIN];
  __shared__ float sP[256], sB[256];
  __shared__ int cP[256], cN[256];
  int b = blockIdx.y, tid = threadIdx.x;
  if (tid < T) st[tid] = tboxes[b*T+tid];
  for (int i = tid; i < NBIN; i += 256) h[i] = 0;
  __syncthreads();
  size_t ibase = (size_t)b*A + (size_t)blockIdx.x*4096;
  float fsum=0.f, bsum=0.f; int cpos=0, cneg=0;
  for (int it = 0; it < 4; ++it) {
    int off = it*1024 + tid*4;
    float4 mi4 = *(const float4*)(maxIou + ibase + off);
    float4 cf4 = *(const float4*)(conf_pred + ibase + off);
    uchar4 fc4 = *(const uchar4*)(forced + ibase + off);
    uchar4 bt4 = *(const uchar4*)(bestT + ibase + off);
    float mis[4]={mi4.x,mi4.y,mi4.z,mi4.w};
    float cfs[4]={cf4.x,cf4.y,cf4.z,cf4.w};
    unsigned char fcs[4]={fc4.x,fc4.y,fc4.z,fc4.w};
    unsigned char bts[4]={bt4.x,bt4.y,bt4.z,bt4.w};
    float nc[4];
    #pragma unroll
    for (int j=0;j<4;++j) {
      float maxI = mis[j], conf = cfs[j];
      bool isPos = (maxI >= 0.5f) || (fcs[j] != 0);
      bool isNeg = (maxI < 0.4f) && !isPos;
      nc[j] = isNeg ? conf : -1.f;
      if (isNeg) {
        int bin = min(NBIN-1, (int)(conf*1024.f));
        atomicAdd(&h[bin], 1u);
        cneg++;
      }
      if (isPos) {
        cpos++;
        float ptc = fminf(fmaxf(conf, EPSF), 1.f-EPSF);
        float om = 1.f - conf;
        fsum += -0.25f * om * om * logf(ptc);
        float4 pb = bbox_pred[ibase + off + j];
        float4 m = st[bts[j]];
        float ix1=fmaxf(pb.x,m.x), iy1=fmaxf(pb.y,m.y);
        float ix2=fminf(pb.z,m.z), iy2=fminf(pb.w,m.w);
        float inter=fmaxf(ix2-ix1,0.f)*fmaxf(iy2-iy1,0.f);
        float a1=(pb.z-pb.x)*(pb.w-pb.y);
        float a2=(m.z-m.x)*(m.w-m.y);
        float uni = a1 + a2 - inter;
        float iou = inter/(uni+EPSF);
        float ex1=fminf(pb.x,m.x), ey1=fminf(pb.y,m.y);
        float ex2=fmaxf(pb.z,m.z), ey2=fmaxf(pb.w,m.w);
        float enc=(ex2-ex1)*(ey2-ey1);
        float giou = iou - (enc-uni)/(enc+EPSF);
        float l1 = fabsf(pb.x-m.x)+fabsf(pb.y-m.y)+fabsf(pb.z-m.z)+fabsf(pb.w-m.w);
        bsum += (1.f - giou) + 0.125f*l1;
      }
    }
    *(float4*)(negConf + ibase + off) = make_float4(nc[0],nc[1],nc[2],nc[3]);
  }
  sP[tid]=fsum; sB[tid]=bsum; cP[tid]=cpos; cN[tid]=cneg;
  __syncthreads();
  for (int s=128;s>0;s>>=1) {
    if (tid<s){ sP[tid]+=sP[tid+s]; sB[tid]+=sB[tid+s]; cP[tid]+=cP[tid+s]; cN[tid]+=cN[tid+s]; }
    __syncthreads();
  }
  if (tid==0) {
    atomicAdd(&accPos[b], sP[0]);
    atomicAdd(&accBbox[b], sB[0]);
    atomicAdd(&cntPos[b], (unsigned)cP[0]);
    atomicAdd(&cntNeg[b], (unsigned)cN[0]);
  }
  for (int i = tid; i < NBIN; i += 256)
    if (h[i]) atomicAdd(&gh[b*NBIN + i], h[i]);
}

// 16 blocks/image: redundant parallel hist-scan -> selB/krem, then stream slice:
// focal-sum for bins > selB, collect cutoff-bucket members to global.
__global__ __launch_bounds__(256) void k_collect(
    const float* __restrict__ negConf, const unsigned* __restrict__ gh,
    const unsigned* __restrict__ cntPos, const unsigned* __restrict__ cntNeg,
    float* __restrict__ sumHi, unsigned* __restrict__ bucketCnt,
    unsigned* __restrict__ bucketBuf, unsigned* __restrict__ kremG,
    int A, int B) {
  __shared__ unsigned hh[NBIN];
  __shared__ unsigned partial[256];
  __shared__ int sSelB, sKrem;
  __shared__ float sred[256];
  int b = blockIdx.y, tid = threadIdx.x;
  int np = (int)cntPos[b], nn = (int)cntNeg[b];
  int ratio = (np>0) ? min(3, A/np) : 0;
  int k = min(ratio*np, nn);
  if (k <= 0) return;
  for (int i = tid; i < NBIN; i += 256) hh[i] = gh[b*NBIN+i];
  __syncthreads();
  unsigned own = hh[4*tid] + hh[4*tid+1] + hh[4*tid+2] + hh[4*tid+3];
  partial[tid] = own;
  __syncthreads();
  for (int off=1; off<256; off<<=1) {       // inclusive suffix scan (parallel)
    unsigned v = (tid+off<256) ? partial[tid+off] : 0u;
    __syncthreads();
    partial[tid] += v;
    __syncthreads();
  }
  {
    unsigned running = partial[tid] - own;  // sum of bins >= 4(tid+1)
    #pragma unroll
    for (int j=3;j>=0;--j) {
      unsigned incl = running + hh[4*tid+j];
      if (incl >= (unsigned)k && running < (unsigned)k) { sSelB = 4*tid+j; sKrem = k-(int)running; }
      running = incl;
    }
  }
  __syncthreads();
  int selB = sSelB, krem = sKrem;
  if (blockIdx.x==0 && tid==0) kremG[b] = (unsigned)krem;
  const float4* nc4 = (const float4*)(negConf + (size_t)b*A);
  int per4 = (A/4) / gridDim.x;
  int i0 = blockIdx.x * per4;
  float ls = 0.f;
  for (int i = tid; i < per4; i += 256) {
    float4 c4 = nc4[i0+i];
    float cs[4]={c4.x,c4.y,c4.z,c4.w};
    #pragma unroll
    for (int j=0;j<4;++j) {
      float c = cs[j];
      if (c >= 0.f) {
        int bin = min(NBIN-1, (int)(c*1024.f));
        if (bin > selB) ls += focal_neg(c);
        else if (bin == selB) {
          unsigned idx = atomicAdd(&bucketCnt[b], 1u);
          if (idx < CAP) bucketBuf[b*CAP+idx] = __float_as_uint(c);
        }
      }
    }
  }
  sred[tid]=ls; __syncthreads();
  for (int s=128;s>0;s>>=1){ if(tid<s) sred[tid]+=sred[tid+s]; __syncthreads(); }
  if (tid==0) atomicAdd(&sumHi[b], sred[0]);
}

// one block/image: fully parallel radix-select over the small bucket -> exact
// theta; finalize scalar.
__global__ __launch_bounds__(256) void k_resolve(
    const unsigned* __restrict__ bucketBuf, const unsigned* __restrict__ bucketCnt,
    const unsigned* __restrict__ kremG, const float* __restrict__ sumHi,
    const float* __restrict__ accPos, const float* __restrict__ accBbox,
    const unsigned* __restrict__ cntPos, const unsigned* __restrict__ cntNeg,
    float* __restrict__ out, int A, int B) {
  __shared__ unsigned hist[256], suff[256];
  __shared__ unsigned sSel; __shared__ int sKr;
  __shared__ float sred[256]; __shared__ unsigned sredc[256];
  int b = blockIdx.x, tid = threadIdx.x;
  int np = (int)cntPos[b], nn = (int)cntNeg[b];
  int ratio = (np>0) ? min(3, A/np) : 0;
  int k = min(ratio*np, nn);
  float negSum = 0.f;
  if (k > 0) {
    int m = min((int)bucketCnt[b], CAP);
    int kr = (int)kremG[b];
    unsigned prefix = 0;
    const unsigned* buf = bucketBuf + b*CAP;
    for (int r=0;r<4;++r) {
      int shift = 24-8*r;
      unsigned maskHi = (r==0) ? 0u : (0xFFFFFFFFu << (32-8*r));
      hist[tid] = 0; __syncthreads();
      for (int i=tid;i<m;i+=256) {
        unsigned v = buf[i];
        if ((v & maskHi) == prefix) atomicAdd(&hist[(v>>shift)&0xFFu], 1u);
      }
      __syncthreads();
      suff[tid] = hist[tid]; __syncthreads();
      for (int off=1;off<256;off<<=1) {
        unsigned v = (tid+off<256) ? suff[tid+off] : 0u;
        __syncthreads(); suff[tid] += v; __syncthreads();
      }
      unsigned incl = suff[tid];
      unsigned above = (tid==255) ? 0u : suff[tid+1];
      if (incl >= (unsigned)kr && above < (unsigned)kr) { sSel=(unsigned)tid; sKr = kr-(int)above; }
      __syncthreads();
      prefix |= (sSel << shift); kr = sKr;
      __syncthreads();
    }
    unsigned theta = prefix;
    float ls=0.f; unsigned lc=0;
    for (int i=tid;i<m;i+=256) {
      unsigned v = buf[i];
      if (v > theta) { ls += focal_neg(__uint_as_float(v)); lc++; }
    }
    sred[tid]=ls; sredc[tid]=lc; __syncthreads();
    for (int s=128;s>0;s>>=1){
      if (tid<s){ sred[tid]+=sred[tid+s]; sredc[tid]+=sredc[tid+s]; }
      __syncthreads();
    }
    int krem = (int)kremG[b];
    negSum = sumHi[b] + sred[0] + (float)(krem-(int)sredc[0]) * focal_neg(__uint_as_float(theta));
  }
  if (tid==0) {
    float confL = (accPos[b] + negSum) / (float)max(np + k, 1);
    float bboxL = accBbox[b] / (float)(np > 0 ? np : 1);
    atomicAdd(out, (confL + bboxL) / (float)B);
  }
}

extern "C" void kernel_launch(void* const* d_in, const int* in_sizes, int n_in,
                              void* d_out, int out_size, void* d_ws, size_t ws_size,
                              hipStream_t stream) {
  const float4* bbox_pred = (const float4*)d_in[0];
  const float*  conf_pred = (const float*)d_in[1];
  const float4* anchors   = (const float4*)d_in[2];
  const float4* tboxes    = (const float4*)d_in[3];
  float* out = (float*)d_out;

  int A = in_sizes[2] / 4;          // 65536
  int B = in_sizes[1] / A;          // 16
  int T = in_sizes[3] / (4 * B);    // 32
  int nch = A / ACH;                // 128
  size_t BA = (size_t)B * A;

  // ws: negConf f32[BA] | maxIou f32[BA] | forced u8[BA] | bestT u8[BA] |
  //     parts[B*T*nch] | gh u32[B*NBIN] | bucketBuf u32[B*CAP] | small accs
  float* negConf = (float*)d_ws;
  float* maxIou  = negConf + BA;
  unsigned char* forced = (unsigned char*)(maxIou + BA);
  unsigned char* bestT  = forced + BA;
  Part* parts = (Part*)(bestT + BA);
  unsigned* gh = (unsigned*)(parts + (size_t)B*T*nch);
  unsigned* bucketBuf = gh + (size_t)B*NBIN;
  float* accPos  = (float*)(bucketBuf + (size_t)B*CAP);
  float* accBbox = accPos + B;
  unsigned* cntPos = (unsigned*)(accBbox + B);
  unsigned* cntNeg = cntPos + B;
  float* sumHi = (float*)(cntNeg + B);
  unsigned* bucketCnt = (unsigned*)(sumHi + B);
  unsigned* kremG = bucketCnt + B;

  int nfw = (int)(BA / 4);
  int ngh = B * NBIN;
  int nacc = 7 * B;
  k_zero<<<(nfw + 255)/256, 256, 0, stream>>>((unsigned*)forced, nfw, gh, ngh,
                                              (unsigned*)accPos, nacc, out);

  dim3 gf((unsigned)nch, (unsigned)B);
  k_fpart<<<gf, 256, 0, stream>>>(anchors, tboxes, parts, maxIou, bestT, A, T, nch);
  k_fmerge<<<B*T, 64, 0, stream>>>(parts, anchors, tboxes, forced, A, T, nch);

  dim3 g2((unsigned)(A/4096), (unsigned)B);
  k_anchor2<<<g2, 256, 0, stream>>>(bbox_pred, conf_pred, tboxes, forced, maxIou, bestT,
                                    negConf, gh, accPos, accBbox, cntPos, cntNeg, A, T);

  dim3 gc(16, (unsigned)B);
  k_collect<<<gc, 256, 0, stream>>>(negConf, gh, cntPos, cntNeg,
                                    sumHi, bucketCnt, bucketBuf, kremG, A, B);
  k_resolve<<<B, 256, 0, stream>>>(bucketBuf, bucketCnt, kremG, sumHi,
                                   accPos, accBbox, cntPos, cntNeg, out, A, B);
}

// Round 9
// 82.386 us; speedup vs baseline: 4.1318x; 1.2640x over previous
//
#include <hip/hip_runtime.h>
#include <math.h>

#define EPSF 1e-6f
#define ACH 512      // anchors per k_fpart block
#define NBIN 1024    // conf histogram bins
#define CAP 8192     // cutoff-bucket capacity (expected ~64 for uniform conf)
#define CAPB 64      // per-target per-block candidate buffer
#define BIASU 0x4000000000000000ull

struct Part { unsigned long long q0, q1, q2, cand; };

__device__ __forceinline__ double u2d(unsigned long long x){return __longlong_as_double((long long)x);}
__device__ __forceinline__ unsigned long long d2u(double x){return (unsigned long long)__double_as_longlong(x);}

// branchless sorted-insert into descending triple; keys are positive doubles
// (bit62 bias, f32-iou bits occupy bits 32..61) so f64 order == u64 order.
__device__ __forceinline__ void ins3d(double p, double &q0, double &q1, double &q2) {
  double n0 = fmax(q0,p), x = fmin(q0,p);
  double n1 = fmax(q1,x), y = fmin(q1,x);
  double n2 = fmax(q2,y);
  q0=n0; q1=n1; q2=n2;
}

__device__ __forceinline__ float focal_neg(float c) {
  float pt = 1.f - c;
  float ptc = fminf(fmaxf(pt, EPSF), 1.f - EPSF);
  float om = 1.f - pt;
  return -0.75f * om * om * logf(ptc);
}

// Fused per-(512-anchor-chunk, image) kernel. Each thread holds 2 anchors in
// registers; targets are block-uniform loads (SGPR). One IoU core per pair
// feeds BOTH per-anchor argmax (cross-mult compare; precise div at end, np-
// bitwise) and the candidate test (iou>0.3; rcp-approx key, ordering only).
// Candidates (~2% of lanes) push packed keys to per-target LDS buffers; a
// 32-thread merge folds them to top-3. Exact counts always; exact fallback
// rescans any overflowed target (never taken in practice).
// Also absorbs k_zero: zeroes forced slice, per-image hist, accs, out.
__global__ __launch_bounds__(256) void k_fpart(
    const float4* __restrict__ anchors, const float4* __restrict__ tboxes,
    Part* __restrict__ parts, float* __restrict__ maxIou, unsigned char* __restrict__ bestT,
    unsigned char* __restrict__ forced, unsigned* __restrict__ gh,
    unsigned* __restrict__ accW, int naccW, float* __restrict__ out,
    int A, int T, int nch) {
  __shared__ unsigned long long buf[32][CAPB+1];
  __shared__ unsigned cnt[32];
  int chunk = blockIdx.x, b = blockIdx.y;
  int tid = threadIdx.x;
  int base = chunk * ACH;
  // ---- absorbed zero duties ----
  if (tid < 32) cnt[tid] = 0;
  if (tid < 128) ((unsigned*)(forced + (size_t)b*A + base))[tid] = 0u;
  if (chunk < 4) gh[b*NBIN + chunk*256 + tid] = 0u;
  if (chunk == 4 && b == 0) {
    if (tid < naccW) accW[tid] = 0u;
    if (tid == 0) out[0] = 0.f;
  }
  // ---- anchors to registers (coalesced) ----
  int i0 = base + tid, i1 = base + tid + 256;
  float4 a0 = anchors[i0], a1 = anchors[i1];
  float ar0 = (a0.z-a0.x)*(a0.w-a0.y);
  float ar1 = (a1.z-a1.x)*(a1.w-a1.y);
  float g0 = 0.3f*ar0, g1 = 0.3f*ar1;
  __syncthreads();           // cnt ready before pushes
  float bn0=-1.f, bd0=1.f; float bn1=-1.f, bd1=1.f;
  int bt0=0, bt1=0;
  #pragma unroll 4
  for (int tt = 0; tt < T; ++tt) {
    float4 tv = tboxes[b*T + tt];          // uniform -> s_load/SGPR
    float ta = (tv.z-tv.x)*(tv.w-tv.y);
    float cH = 0.3f*(ta + EPSF) - 1e-6f;   // conservative guard constant
    { // anchor 0
      float ix1=fmaxf(a0.x,tv.x), iy1=fmaxf(a0.y,tv.y);
      float ix2=fminf(a0.z,tv.z), iy2=fminf(a0.w,tv.w);
      float inter=fmaxf(ix2-ix1,0.f)*fmaxf(iy2-iy1,0.f);
      float u=(ar0+ta)-inter, d=u+EPSF;    // same op order as np
      bool gt = inter*bd0 > bn0*d;         // first-occurrence argmax kept on ties
      bn0=gt?inter:bn0; bd0=gt?d:bd0; bt0=gt?tt:bt0;
      if (1.3f*inter >= g0 + cH) {         // superset of iou>0.3
        float iou = inter * __builtin_amdgcn_rcpf(d);
        if (iou > 0.3f) {
          unsigned slot = atomicAdd(&cnt[tt], 1u);
          if (slot < CAPB)
            buf[tt][slot] = ((unsigned long long)__float_as_uint(iou)<<32)
                          | (unsigned long long)(0xFFFFFFFFu-(unsigned)i0) | BIASU;
        }
      }
    }
    { // anchor 1
      float ix1=fmaxf(a1.x,tv.x), iy1=fmaxf(a1.y,tv.y);
      float ix2=fminf(a1.z,tv.z), iy2=fminf(a1.w,tv.w);
      float inter=fmaxf(ix2-ix1,0.f)*fmaxf(iy2-iy1,0.f);
      float u=(ar1+ta)-inter, d=u+EPSF;
      bool gt = inter*bd1 > bn1*d;
      bn1=gt?inter:bn1; bd1=gt?d:bd1; bt1=gt?tt:bt1;
      if (1.3f*inter >= g1 + cH) {
        float iou = inter * __builtin_amdgcn_rcpf(d);
        if (iou > 0.3f) {
          unsigned slot = atomicAdd(&cnt[tt], 1u);
          if (slot < CAPB)
            buf[tt][slot] = ((unsigned long long)__float_as_uint(iou)<<32)
                          | (unsigned long long)(0xFFFFFFFFu-(unsigned)i1) | BIASU;
        }
      }
    }
  }
  size_t gb = (size_t)b * A;
  maxIou[gb+i0] = bn0/bd0; bestT[gb+i0] = (unsigned char)bt0;  // precise, np-bitwise
  maxIou[gb+i1] = bn1/bd1; bestT[gb+i1] = (unsigned char)bt1;
  __syncthreads();
  const double BIASD = u2d(BIASU);
  if (tid < 32 && tid < T) {               // per-target merge (entries ~10)
    unsigned n = cnt[tid];
    if (n <= CAPB) {
      double q0=BIASD, q1=BIASD, q2=BIASD;
      for (unsigned j = 0; j < n; ++j) ins3d(u2d(buf[tid][j]), q0,q1,q2);
      Part p; p.q0=d2u(q0); p.q1=d2u(q1); p.q2=d2u(q2); p.cand=n;
      parts[(b*T+tid)*nch+chunk] = p;
    }
  }
  if (tid < 64) {                          // exact overflow fallback (~never)
    unsigned long long ovf = __ballot(tid < T && cnt[tid] > CAPB);
    while (ovf) {
      int t = __ffsll(ovf) - 1;
      ovf &= ovf - 1;
      float4 tv = tboxes[b*T + t];
      float ta = (tv.z-tv.x)*(tv.w-tv.y);
      double q0=BIASD, q1=BIASD, q2=BIASD;
      for (int j = 0; j < ACH; j += 64) {
        int idx = base + j + tid;
        float4 an = anchors[idx];
        float aa = (an.z-an.x)*(an.w-an.y);
        float ix1=fmaxf(an.x,tv.x), iy1=fmaxf(an.y,tv.y);
        float ix2=fminf(an.z,tv.z), iy2=fminf(an.w,tv.w);
        float inter=fmaxf(ix2-ix1,0.f)*fmaxf(iy2-iy1,0.f);
        float iou = inter / ((aa+ta)-inter + EPSF);
        if (iou > 0.3f) {
          unsigned long long pk = ((unsigned long long)__float_as_uint(iou)<<32)
                                | (unsigned long long)(0xFFFFFFFFu-(unsigned)idx) | BIASU;
          ins3d(u2d(pk), q0,q1,q2);
        }
      }
      for (int s=1;s<64;s<<=1) {
        double r0=__shfl_xor(q0,s,64), r1=__shfl_xor(q1,s,64), r2=__shfl_xor(q2,s,64);
        ins3d(r0,q0,q1,q2); ins3d(r1,q0,q1,q2); ins3d(r2,q0,q1,q2);
      }
      if (tid == 0) {
        Part p; p.q0=d2u(q0); p.q1=d2u(q1); p.q2=d2u(q2); p.cand=cnt[t];
        parts[(b*T+t)*nch+chunk] = p;
      }
    }
  }
}

// one wave per (b,t): merge nch chunk-partials. cand>=1: forced = top-min(3,cand)
// (== reference, since forced set is within candidates). cand==0: exact argmax.
__global__ __launch_bounds__(64) void k_fmerge(
    const Part* __restrict__ parts, const float4* __restrict__ anchors,
    const float4* __restrict__ tboxes, unsigned char* __restrict__ forced,
    int A, int T, int nch) {
  int p = blockIdx.x;            // b*T + t
  int b = p / T, t = p - b*T;
  int lane = threadIdx.x;
  const double BIASD = u2d(BIASU);
  double q0=BIASD, q1=BIASD, q2=BIASD;
  unsigned long long cand = 0;
  for (int c = lane; c < nch; c += 64) {
    Part pp = parts[p*nch + c];
    ins3d(u2d(pp.q0),q0,q1,q2); ins3d(u2d(pp.q1),q0,q1,q2); ins3d(u2d(pp.q2),q0,q1,q2);
    cand += pp.cand;
  }
  for (int s = 1; s < 64; s <<= 1) {
    double r0=__shfl_xor(q0,s,64), r1=__shfl_xor(q1,s,64), r2=__shfl_xor(q2,s,64);
    unsigned long long rc=__shfl_xor(cand,s,64);
    ins3d(r0,q0,q1,q2); ins3d(r1,q0,q1,q2); ins3d(r2,q0,q1,q2);
    cand += rc;
  }
  if (cand == 0) {               // wave-uniform, ~never taken
    float4 tv = tboxes[b*T + t];
    float ta = (tv.z-tv.x)*(tv.w-tv.y);
    double m = BIASD;
    for (int a = lane; a < A; a += 64) {
      float4 an = anchors[a];
      float a1 = (an.z-an.x)*(an.w-an.y);
      float ix1=fmaxf(an.x,tv.x), iy1=fmaxf(an.y,tv.y);
      float ix2=fminf(an.z,tv.z), iy2=fminf(an.w,tv.w);
      float inter=fmaxf(ix2-ix1,0.f)*fmaxf(iy2-iy1,0.f);
      float u = (a1 + ta) - inter;
      float iou = inter / (u + EPSF);
      unsigned long long pk = ((unsigned long long)__float_as_uint(iou)<<32)
                            | (unsigned long long)(0xFFFFFFFFu-(unsigned)a) | BIASU;
      m = fmax(m, u2d(pk));
    }
    for (int s = 1; s < 64; s <<= 1) m = fmax(m, __shfl_xor(m, s, 64));
    if (lane == 0) {
      unsigned idx = 0xFFFFFFFFu - (unsigned)(d2u(m) & 0xFFFFFFFFull);
      forced[(size_t)b*A + idx] = 1;
    }
  } else if (lane == 0) {
    int kt = cand > 3 ? 3 : (int)cand;
    unsigned long long tp[3] = {d2u(q0), d2u(q1), d2u(q2)};
    for (int j = 0; j < kt; ++j) {
      unsigned idx = 0xFFFFFFFFu - (unsigned)(tp[j] & 0xFFFFFFFFull);
      forced[(size_t)b*A + idx] = 1;
    }
  }
}

// streaming: 16 anchors/thread. Reads maxIou/bestT/forced/conf (+bbox for positives),
// writes negConf, builds per-image conf histogram (LDS->global), accumulates
// focal/bbox sums + counts.
__global__ __launch_bounds__(256) void k_anchor2(
    const float4* __restrict__ bbox_pred, const float* __restrict__ conf_pred,
    const float4* __restrict__ tboxes,
    const unsigned char* __restrict__ forced, const float* __restrict__ maxIou,
    const unsigned char* __restrict__ bestT,
    float* __restrict__ negConf, unsigned* __restrict__ gh,
    float* __restrict__ accPos, float* __restrict__ accBbox,
    unsigned* __restrict__ cntPos, unsigned* __restrict__ cntNeg,
    int A, int T) {
  __shared__ float4 st[32];
  __shared__ unsigned h[NBIN];
  __shared__ float sP[256], sB[256];
  __shared__ int cP[256], cN[256];
  int b = blockIdx.y, tid = threadIdx.x;
  if (tid < T) st[tid] = tboxes[b*T+tid];
  for (int i = tid; i < NBIN; i += 256) h[i] = 0;
  __syncthreads();
  size_t ibase = (size_t)b*A + (size_t)blockIdx.x*4096;
  float fsum=0.f, bsum=0.f; int cpos=0, cneg=0;
  for (int it = 0; it < 4; ++it) {
    int off = it*1024 + tid*4;
    float4 mi4 = *(const float4*)(maxIou + ibase + off);
    float4 cf4 = *(const float4*)(conf_pred + ibase + off);
    uchar4 fc4 = *(const uchar4*)(forced + ibase + off);
    uchar4 bt4 = *(const uchar4*)(bestT + ibase + off);
    float mis[4]={mi4.x,mi4.y,mi4.z,mi4.w};
    float cfs[4]={cf4.x,cf4.y,cf4.z,cf4.w};
    unsigned char fcs[4]={fc4.x,fc4.y,fc4.z,fc4.w};
    unsigned char bts[4]={bt4.x,bt4.y,bt4.z,bt4.w};
    float nc[4];
    #pragma unroll
    for (int j=0;j<4;++j) {
      float maxI = mis[j], conf = cfs[j];
      bool isPos = (maxI >= 0.5f) || (fcs[j] != 0);
      bool isNeg = (maxI < 0.4f) && !isPos;
      nc[j] = isNeg ? conf : -1.f;
      if (isNeg) {
        int bin = min(NBIN-1, (int)(conf*1024.f));
        atomicAdd(&h[bin], 1u);
        cneg++;
      }
      if (isPos) {
        cpos++;
        float ptc = fminf(fmaxf(conf, EPSF), 1.f-EPSF);
        float om = 1.f - conf;
        fsum += -0.25f * om * om * logf(ptc);
        float4 pb = bbox_pred[ibase + off + j];
        float4 m = st[bts[j]];
        float ix1=fmaxf(pb.x,m.x), iy1=fmaxf(pb.y,m.y);
        float ix2=fminf(pb.z,m.z), iy2=fminf(pb.w,m.w);
        float inter=fmaxf(ix2-ix1,0.f)*fmaxf(iy2-iy1,0.f);
        float a1=(pb.z-pb.x)*(pb.w-pb.y);
        float a2=(m.z-m.x)*(m.w-m.y);
        float uni = a1 + a2 - inter;
        float iou = inter/(uni+EPSF);
        float ex1=fminf(pb.x,m.x), ey1=fminf(pb.y,m.y);
        float ex2=fmaxf(pb.z,m.z), ey2=fmaxf(pb.w,m.w);
        float enc=(ex2-ex1)*(ey2-ey1);
        float giou = iou - (enc-uni)/(enc+EPSF);
        float l1 = fabsf(pb.x-m.x)+fabsf(pb.y-m.y)+fabsf(pb.z-m.z)+fabsf(pb.w-m.w);
        bsum += (1.f - giou) + 0.125f*l1;
      }
    }
    *(float4*)(negConf + ibase + off) = make_float4(nc[0],nc[1],nc[2],nc[3]);
  }
  sP[tid]=fsum; sB[tid]=bsum; cP[tid]=cpos; cN[tid]=cneg;
  __syncthreads();
  for (int s=128;s>0;s>>=1) {
    if (tid<s){ sP[tid]+=sP[tid+s]; sB[tid]+=sB[tid+s]; cP[tid]+=cP[tid+s]; cN[tid]+=cN[tid+s]; }
    __syncthreads();
  }
  if (tid==0) {
    atomicAdd(&accPos[b], sP[0]);
    atomicAdd(&accBbox[b], sB[0]);
    atomicAdd(&cntPos[b], (unsigned)cP[0]);
    atomicAdd(&cntNeg[b], (unsigned)cN[0]);
  }
  for (int i = tid; i < NBIN; i += 256)
    if (h[i]) atomicAdd(&gh[b*NBIN + i], h[i]);
}

// 16 blocks/image: redundant parallel hist-scan -> selB/krem, then stream slice:
// focal-sum for bins > selB, collect cutoff-bucket members to global.
__global__ __launch_bounds__(256) void k_collect(
    const float* __restrict__ negConf, const unsigned* __restrict__ gh,
    const unsigned* __restrict__ cntPos, const unsigned* __restrict__ cntNeg,
    float* __restrict__ sumHi, unsigned* __restrict__ bucketCnt,
    unsigned* __restrict__ bucketBuf, unsigned* __restrict__ kremG,
    int A, int B) {
  __shared__ unsigned hh[NBIN];
  __shared__ unsigned partial[256];
  __shared__ int sSelB, sKrem;
  __shared__ float sred[256];
  int b = blockIdx.y, tid = threadIdx.x;
  int np = (int)cntPos[b], nn = (int)cntNeg[b];
  int ratio = (np>0) ? min(3, A/np) : 0;
  int k = min(ratio*np, nn);
  if (k <= 0) return;
  for (int i = tid; i < NBIN; i += 256) hh[i] = gh[b*NBIN+i];
  __syncthreads();
  unsigned own = hh[4*tid] + hh[4*tid+1] + hh[4*tid+2] + hh[4*tid+3];
  partial[tid] = own;
  __syncthreads();
  for (int off=1; off<256; off<<=1) {       // inclusive suffix scan (parallel)
    unsigned v = (tid+off<256) ? partial[tid+off] : 0u;
    __syncthreads();
    partial[tid] += v;
    __syncthreads();
  }
  {
    unsigned running = partial[tid] - own;  // sum of bins >= 4(tid+1)
    #pragma unroll
    for (int j=3;j>=0;--j) {
      unsigned incl = running + hh[4*tid+j];
      if (incl >= (unsigned)k && running < (unsigned)k) { sSelB = 4*tid+j; sKrem = k-(int)running; }
      running = incl;
    }
  }
  __syncthreads();
  int selB = sSelB, krem = sKrem;
  if (blockIdx.x==0 && tid==0) kremG[b] = (unsigned)krem;
  const float4* nc4 = (const float4*)(negConf + (size_t)b*A);
  int per4 = (A/4) / gridDim.x;
  int i0 = blockIdx.x * per4;
  float ls = 0.f;
  for (int i = tid; i < per4; i += 256) {
    float4 c4 = nc4[i0+i];
    float cs[4]={c4.x,c4.y,c4.z,c4.w};
    #pragma unroll
    for (int j=0;j<4;++j) {
      float c = cs[j];
      if (c >= 0.f) {
        int bin = min(NBIN-1, (int)(c*1024.f));
        if (bin > selB) ls += focal_neg(c);
        else if (bin == selB) {
          unsigned idx = atomicAdd(&bucketCnt[b], 1u);
          if (idx < CAP) bucketBuf[b*CAP+idx] = __float_as_uint(c);
        }
      }
    }
  }
  sred[tid]=ls; __syncthreads();
  for (int s=128;s>0;s>>=1){ if(tid<s) sred[tid]+=sred[tid+s]; __syncthreads(); }
  if (tid==0) atomicAdd(&sumHi[b], sred[0]);
}

// one block/image: fully parallel radix-select over the small bucket -> exact
// theta; finalize scalar.
__global__ __launch_bounds__(256) void k_resolve(
    const unsigned* __restrict__ bucketBuf, const unsigned* __restrict__ bucketCnt,
    const unsigned* __restrict__ kremG, const float* __restrict__ sumHi,
    const float* __restrict__ accPos, const float* __restrict__ accBbox,
    const unsigned* __restrict__ cntPos, const unsigned* __restrict__ cntNeg,
    float* __restrict__ out, int A, int B) {
  __shared__ unsigned hist[256], suff[256];
  __shared__ unsigned sSel; __shared__ int sKr;
  __shared__ float sred[256]; __shared__ unsigned sredc[256];
  int b = blockIdx.x, tid = threadIdx.x;
  int np = (int)cntPos[b], nn = (int)cntNeg[b];
  int ratio = (np>0) ? min(3, A/np) : 0;
  int k = min(ratio*np, nn);
  float negSum = 0.f;
  if (k > 0) {
    int m = min((int)bucketCnt[b], CAP);
    int kr = (int)kremG[b];
    unsigned prefix = 0;
    const unsigned* buf = bucketBuf + b*CAP;
    for (int r=0;r<4;++r) {
      int shift = 24-8*r;
      unsigned maskHi = (r==0) ? 0u : (0xFFFFFFFFu << (32-8*r));
      hist[tid] = 0; __syncthreads();
      for (int i=tid;i<m;i+=256) {
        unsigned v = buf[i];
        if ((v & maskHi) == prefix) atomicAdd(&hist[(v>>shift)&0xFFu], 1u);
      }
      __syncthreads();
      suff[tid] = hist[tid]; __syncthreads();
      for (int off=1;off<256;off<<=1) {
        unsigned v = (tid+off<256) ? suff[tid+off] : 0u;
        __syncthreads(); suff[tid] += v; __syncthreads();
      }
      unsigned incl = suff[tid];
      unsigned above = (tid==255) ? 0u : suff[tid+1];
      if (incl >= (unsigned)kr && above < (unsigned)kr) { sSel=(unsigned)tid; sKr = kr-(int)above; }
      __syncthreads();
      prefix |= (sSel << shift); kr = sKr;
      __syncthreads();
    }
    unsigned theta = prefix;
    float ls=0.f; unsigned lc=0;
    for (int i=tid;i<m;i+=256) {
      unsigned v = buf[i];
      if (v > theta) { ls += focal_neg(__uint_as_float(v)); lc++; }
    }
    sred[tid]=ls; sredc[tid]=lc; __syncthreads();
    for (int s=128;s>0;s>>=1){
      if (tid<s){ sred[tid]+=sred[tid+s]; sredc[tid]+=sredc[tid+s]; }
      __syncthreads();
    }
    int krem = (int)kremG[b];
    negSum = sumHi[b] + sred[0] + (float)(krem-(int)sredc[0]) * focal_neg(__uint_as_float(theta));
  }
  if (tid==0) {
    float confL = (accPos[b] + negSum) / (float)max(np + k, 1);
    float bboxL = accBbox[b] / (float)(np > 0 ? np : 1);
    atomicAdd(out, (confL + bboxL) / (float)B);
  }
}

extern "C" void kernel_launch(void* const* d_in, const int* in_sizes, int n_in,
                              void* d_out, int out_size, void* d_ws, size_t ws_size,
                              hipStream_t stream) {
  const float4* bbox_pred = (const float4*)d_in[0];
  const float*  conf_pred = (const float*)d_in[1];
  const float4* anchors   = (const float4*)d_in[2];
  const float4* tboxes    = (const float4*)d_in[3];
  float* out = (float*)d_out;

  int A = in_sizes[2] / 4;          // 65536
  int B = in_sizes[1] / A;          // 16
  int T = in_sizes[3] / (4 * B);    // 32
  int nch = A / ACH;                // 128
  size_t BA = (size_t)B * A;

  // ws: negConf f32[BA] | maxIou f32[BA] | forced u8[BA] | bestT u8[BA] |
  //     parts[B*T*nch] | gh u32[B*NBIN] | bucketBuf u32[B*CAP] | small accs
  float* negConf = (float*)d_ws;
  float* maxIou  = negConf + BA;
  unsigned char* forced = (unsigned char*)(maxIou + BA);
  unsigned char* bestT  = forced + BA;
  Part* parts = (Part*)(bestT + BA);
  unsigned* gh = (unsigned*)(parts + (size_t)B*T*nch);
  unsigned* bucketBuf = gh + (size_t)B*NBIN;
  float* accPos  = (float*)(bucketBuf + (size_t)B*CAP);
  float* accBbox = accPos + B;
  unsigned* cntPos = (unsigned*)(accBbox + B);
  unsigned* cntNeg = cntPos + B;
  float* sumHi = (float*)(cntNeg + B);
  unsigned* bucketCnt = (unsigned*)(sumHi + B);
  unsigned* kremG = bucketCnt + B;

  int naccW = 7 * B;   // accPos..kremG contiguous words

  dim3 gf((unsigned)nch, (unsigned)B);
  k_fpart<<<gf, 256, 0, stream>>>(anchors, tboxes, parts, maxIou, bestT,
                                  forced, gh, (unsigned*)accPos, naccW, out, A, T, nch);
  k_fmerge<<<B*T, 64, 0, stream>>>(parts, anchors, tboxes, forced, A, T, nch);

  dim3 g2((unsigned)(A/4096), (unsigned)B);
  k_anchor2<<<g2, 256, 0, stream>>>(bbox_pred, conf_pred, tboxes, forced, maxIou, bestT,
                                    negConf, gh, accPos, accBbox, cntPos, cntNeg, A, T);

  dim3 gc(16, (unsigned)B);
  k_collect<<<gc, 256, 0, stream>>>(negConf, gh, cntPos, cntNeg,
                                    sumHi, bucketCnt, bucketBuf, kremG, A, B);
  k_resolve<<<B, 256, 0, stream>>>(bucketBuf, bucketCnt, kremG, sumHi,
                                   accPos, accBbox, cntPos, cntNeg, out, A, B);
}